// Round 13
// baseline (828.405 us; speedup 1.0000x reference)
//
#include <hip/hip_runtime.h>
#include <stdint.h>
#include <stdio.h>

#define NN 100000
#define NE 500000
#define HID 128
#define NH 4
#define HD 32
#define LL 2
#define SCANB 1024
#define NB ((NN + SCANB - 1) / SCANB)
#define QSLOT 128                 // block-slots per type in qkv_gemm
#define QCHUNKS ((NN + 255) / 256)  // 391 chunks of 256 rows

typedef unsigned short u16;
typedef unsigned char u8;
typedef unsigned int u32;
typedef __attribute__((ext_vector_type(8))) short bfrag;   // 8 bf16 = 4 VGPR
typedef __attribute__((ext_vector_type(4))) float f32x4;
typedef __attribute__((ext_vector_type(2))) float f32x2;

__device__ __forceinline__ float b2f(u32 lo16) {
  union { u32 u; float f; } c; c.u = lo16; return c.f;
}
__device__ __forceinline__ u16 f2b(float f) {
  union { float f; u32 u; } c; c.f = f;
  u32 u = c.u;
  u32 r = (u + 0x7FFFu + ((u >> 16) & 1u)) >> 16;
  return (u16)r;
}
__device__ __forceinline__ float geluf(float x) {
  return 0.5f * x * (1.0f + erff(x * 0.70710678118654752f));
}
__device__ __forceinline__ void up8(uint4 a, float* f) {
  f[0] = b2f(a.x << 16); f[1] = b2f(a.x & 0xFFFF0000u);
  f[2] = b2f(a.y << 16); f[3] = b2f(a.y & 0xFFFF0000u);
  f[4] = b2f(a.z << 16); f[5] = b2f(a.z & 0xFFFF0000u);
  f[6] = b2f(a.w << 16); f[7] = b2f(a.w & 0xFFFF0000u);
}

// ---------------- CSR build (both relations in one launch, blockIdx.y = r) ----
__global__ __launch_bounds__(256) void csr_count(const int* __restrict__ e0,
                                                 const int* __restrict__ e1,
                                                 int* __restrict__ deg) {
  int r = blockIdx.y;
  const int* edges = r ? e1 : e0;
  int e = blockIdx.x * 256 + threadIdx.x;
  if (e < NE) atomicAdd(&deg[(size_t)r * NN + edges[NE + e]], 1);
}

__global__ __launch_bounds__(SCANB) void scan1(const int* __restrict__ deg,
                                               int* __restrict__ rp,
                                               int* __restrict__ bsum) {
  __shared__ int ls[SCANB];
  int r = blockIdx.y;
  int t = threadIdx.x;
  int g = blockIdx.x * SCANB + t;
  int v = (g < NN) ? deg[(size_t)r * NN + g] : 0;
  ls[t] = v;
  __syncthreads();
#pragma unroll
  for (int off = 1; off < SCANB; off <<= 1) {
    int u = (t >= off) ? ls[t - off] : 0;
    __syncthreads();
    ls[t] += u;
    __syncthreads();
  }
  if (g < NN) rp[(size_t)r * (NN + 1) + g] = ls[t] - v;
  if (t == SCANB - 1) bsum[r * NB + blockIdx.x] = ls[t];
}

__global__ __launch_bounds__(128) void scan2(const int* __restrict__ bsum,
                                             int* __restrict__ boff) {
  __shared__ int ls[128];
  int r = blockIdx.y;
  int t = threadIdx.x;
  int v = (t < NB) ? bsum[r * NB + t] : 0;
  ls[t] = v;
  __syncthreads();
#pragma unroll
  for (int off = 1; off < 128; off <<= 1) {
    int u = (t >= off) ? ls[t - off] : 0;
    __syncthreads();
    ls[t] += u;
    __syncthreads();
  }
  if (t < NB) boff[r * NB + t] = ls[t] - v;
}

__global__ __launch_bounds__(SCANB) void scan3(int* __restrict__ rp,
                                               int* __restrict__ cursor,
                                               const int* __restrict__ boff) {
  int r = blockIdx.y;
  int g = blockIdx.x * SCANB + threadIdx.x;
  if (g < NN) {
    int v = rp[(size_t)r * (NN + 1) + g] + boff[r * NB + blockIdx.x];
    rp[(size_t)r * (NN + 1) + g] = v;
    cursor[(size_t)r * NN + g] = v;
  }
  if (g == 0) rp[(size_t)r * (NN + 1) + NN] = NE;
}

__global__ __launch_bounds__(256) void csr_fill(const int* __restrict__ e0,
                                                const int* __restrict__ e1,
                                                int* __restrict__ cursor,
                                                int* __restrict__ s0,
                                                int* __restrict__ s1) {
  int r = blockIdx.y;
  const int* edges = r ? e1 : e0;
  int* srcs = r ? s1 : s0;
  int e = blockIdx.x * 256 + threadIdx.x;
  if (e < NE) {
    int pos = atomicAdd(&cursor[(size_t)r * NN + edges[NE + e]], 1);
    srcs[pos] = edges[e];
  }
}

// ---------------- degree sort (two-level counting sort, keys 0..63) ----------------
__global__ __launch_bounds__(256) void hist_deg(const int* __restrict__ rp,
                                                int* __restrict__ hist) {
  __shared__ int lh[64];
  int r = blockIdx.y;
  if (threadIdx.x < 64) lh[threadIdx.x] = 0;
  __syncthreads();
  int d = blockIdx.x * 256 + threadIdx.x;
  if (d < NN) {
    const int* rowptr = rp + (size_t)r * (NN + 1);
    int dg = rowptr[d + 1] - rowptr[d];
    atomicAdd(&lh[dg < 63 ? dg : 63], 1);
  }
  __syncthreads();
  if (threadIdx.x < 64 && lh[threadIdx.x])
    atomicAdd(&hist[r * 64 + threadIdx.x], lh[threadIdx.x]);
}

__global__ __launch_bounds__(64) void scan_hist(const int* __restrict__ hist,
                                                int* __restrict__ hcur) {
  __shared__ int ls[64];
  int r = blockIdx.y;
  int t = threadIdx.x;
  int v = hist[r * 64 + t];
  ls[t] = v;
  __syncthreads();
#pragma unroll
  for (int off = 1; off < 64; off <<= 1) {
    int u = (t >= off) ? ls[t - off] : 0;
    __syncthreads();
    ls[t] += u;
    __syncthreads();
  }
  hcur[r * 64 + t] = ls[t] - v;
}

__global__ __launch_bounds__(256) void scatter_deg(const int* __restrict__ rp,
                                                   int* __restrict__ hcur,
                                                   int* __restrict__ o0,
                                                   int* __restrict__ o1) {
  __shared__ int lh[64];
  __shared__ int lbase[64];
  int r = blockIdx.y;
  int* order = r ? o1 : o0;
  if (threadIdx.x < 64) lh[threadIdx.x] = 0;
  __syncthreads();
  int d = blockIdx.x * 256 + threadIdx.x;
  int dg = 0, rank = 0;
  if (d < NN) {
    const int* rowptr = rp + (size_t)r * (NN + 1);
    dg = rowptr[d + 1] - rowptr[d];
    if (dg > 63) dg = 63;
    rank = atomicAdd(&lh[dg], 1);
  }
  __syncthreads();
  if (threadIdx.x < 64)
    lbase[threadIdx.x] = lh[threadIdx.x] ? atomicAdd(&hcur[r * 64 + threadIdx.x], lh[threadIdx.x]) : 0;
  __syncthreads();
  if (d < NN) order[lbase[dg] + rank] = d;
}

// ---------------- weight prep ----------------
__global__ __launch_bounds__(256) void prep_wT(const float* __restrict__ src, size_t srcStride,
                                               u16* __restrict__ dst, size_t dstStride,
                                               const float* __restrict__ bsrc, int bsStride,
                                               float* __restrict__ bdst, int bdStride,
                                               const float* __restrict__ p_rel_q) {
  int m = blockIdx.y;
  const float* S = src + (size_t)m * srcStride;
  u16* D = dst + (size_t)m * dstStride;
  int idx = blockIdx.x * 256 + threadIdx.x;
  int k = idx >> 7, n = idx & 127;
  float v = S[idx];
  if (p_rel_q != nullptr) {
    int l = m >> 1, t = m & 1;
    v *= p_rel_q[((l << 1) | (1 - t)) * NH + (n >> 5)] * 0.17677669529663687f;
  }
  D[(size_t)n * HID + k] = f2b(v);
  if (bsrc != nullptr && blockIdx.x == 0 && threadIdx.x < HID) {
    int col = threadIdx.x;
    float bvv = bsrc[(size_t)m * bsStride + col];
    if (p_rel_q != nullptr) {
      int l = m >> 1, t = m & 1;
      bvv *= p_rel_q[((l << 1) | (1 - t)) * NH + (col >> 5)] * 0.17677669529663687f;
    }
    bdst[(size_t)m * bdStride + col] = bvv;
  }
}

__global__ __launch_bounds__(256) void combine_all(
    const float* __restrict__ Wk, const float* __restrict__ bk,
    const float* __restrict__ Wv, const float* __restrict__ bv,
    const float* __restrict__ a_rel, const float* __restrict__ m_rel,
    u16* __restrict__ wqkvT, float* __restrict__ bqkv) {
  int l = blockIdx.z;
  int t = blockIdx.y >> 1, which = blockIdx.y & 1;
  const float* W  = (which == 0 ? Wk : Wv) + (size_t)(l * 2 + t) * HID * HID;
  const float* b  = (which == 0 ? bk : bv) + (size_t)(l * 2 + t) * HID;
  const float* Ar = (which == 0 ? a_rel : m_rel) + (size_t)(l * 2 + t) * NH * HD * HD;
  u16* Wd = wqkvT + ((size_t)(l * 2 + t) * 3 + 1 + which) * HID * HID;
  float* bd = bqkv + ((size_t)(l * 2 + t) * 3 + 1 + which) * HID;
  int idx = blockIdx.x * 256 + threadIdx.x;
  int i = idx >> 7, col = idx & 127;
  int h = col >> 5, e = col & 31;
  {
    const float* ap = Ar + h * HD * HD + e;
    const float* wp = W + (size_t)i * HID + h * HD;
    float s = 0.f;
#pragma unroll
    for (int d = 0; d < HD; ++d) s += wp[d] * ap[d * HD];
    Wd[(size_t)col * HID + i] = f2b(s);
  }
  if (blockIdx.x == 0 && threadIdx.x < HID) {
    int col2 = threadIdx.x, h2 = col2 >> 5, e2 = col2 & 31;
    const float* ap = Ar + h2 * HD * HD + e2;
    const float* bp = b + h2 * HD;
    float s = 0.f;
#pragma unroll
    for (int d = 0; d < HD; ++d) s += bp[d] * ap[d * HD];
    bd[col2] = s;
  }
}

// ---------------- qkv GEMM: 8 waves, 96KB LDS, one barrier, chunk loop + A-prefetch --
// grid = 2*QSLOT blocks of 512 threads. Block handles chunks c = slot, slot+QSLOT, ...
// of 256 rows (8 waves x 32 rows). LDS read-only after the single barrier.
__global__ __launch_bounds__(512) void qkv_gemm(
    const u16* __restrict__ h0, const u16* __restrict__ h1,
    const u16* __restrict__ WT,      // [t][3][n][k] bf16 (layer slice)
    const float* __restrict__ bias,  // [t][3][128]  (layer slice)
    u16* __restrict__ q0, u16* __restrict__ q1,
    u8* __restrict__ k0, u8* __restrict__ k1,
    u8* __restrict__ v0, u8* __restrict__ v1) {
  __shared__ __align__(16) u16 sW[3 * HID * HID];   // 96 KB: q,k,v weights
  const int t = blockIdx.x >= QSLOT;
  const int slot = t ? blockIdx.x - QSLOT : blockIdx.x;
  const u16* A = t ? h1 : h0;
  const u16* Wg = WT + (size_t)t * 3 * HID * HID;
  const float* bs = bias + (size_t)t * 3 * HID;
  u16* Oq = t ? q1 : q0;
  u8* Ok = t ? k1 : k0;
  u8* Ov = t ? v1 : v0;

  const int lane = threadIdx.x & 63;
  const int wid = threadIdx.x >> 6;          // 0..7
  const int l16 = lane & 15, g = lane >> 4;

  // ---- first chunk's A fragments (in flight with W staging) ----
  int c = slot;
  bfrag af[2][4];
#pragma unroll
  for (int rt = 0; rt < 2; ++rt) {
    int row = c * 256 + wid * 32 + rt * 16 + l16;
    int rl = row < NN ? row : NN - 1;
    const bfrag* ap = (const bfrag*)(A + (size_t)rl * HID);
#pragma unroll
    for (int ks = 0; ks < 4; ++ks) af[rt][ks] = ap[ks * 4 + g];
  }

  // ---- stage all 3 mats: 96 instrs over 8 waves (linear dest, inv-swizzled src) ----
#pragma unroll
  for (int m = 0; m < 3; ++m) {
#pragma unroll
    for (int j = 0; j < 4; ++j) {
      int ins = wid * 4 + j;                  // 0..31 within mat
      int o16 = ins * 64 + lane;
      int row = o16 >> 4, ch = o16 & 15;
      const u16* src = Wg + (size_t)m * HID * HID + (size_t)row * HID + ((ch ^ (row & 7)) << 3);
      u16* dst = sW + (size_t)m * HID * HID + (size_t)ins * 512;
      __builtin_amdgcn_global_load_lds(
          (const __attribute__((address_space(1))) unsigned int*)src,
          (__attribute__((address_space(3))) unsigned int*)dst, 16, 0, 0);
    }
  }
  __syncthreads();   // the ONLY barrier

  while (true) {
    const int cn = c + QSLOT;
    // prefetch next chunk's A while current chunk computes
    bfrag afn[2][4];
    if (cn < QCHUNKS) {
#pragma unroll
      for (int rt = 0; rt < 2; ++rt) {
        int row = cn * 256 + wid * 32 + rt * 16 + l16;
        int rl = row < NN ? row : NN - 1;
        const bfrag* ap = (const bfrag*)(A + (size_t)rl * HID);
#pragma unroll
        for (int ks = 0; ks < 4; ++ks) afn[rt][ks] = ap[ks * 4 + g];
      }
    }

    const int rbase = c * 256 + wid * 32;
#pragma unroll
    for (int m = 0; m < 3; ++m) {
      f32x4 acc[2][8];
#pragma unroll
      for (int rt = 0; rt < 2; ++rt)
#pragma unroll
        for (int ct = 0; ct < 8; ++ct) acc[rt][ct] = (f32x4){0.f, 0.f, 0.f, 0.f};
#pragma unroll
      for (int ct = 0; ct < 8; ++ct) {
        int row = ct * 16 + l16;
        bfrag wf[4];
#pragma unroll
        for (int ks = 0; ks < 4; ++ks)
          wf[ks] = *(const bfrag*)&sW[(size_t)m * HID * HID + (size_t)row * HID +
                                      (((ks * 4 + g) ^ (row & 7)) << 3)];
#pragma unroll
        for (int ks = 0; ks < 4; ++ks)
#pragma unroll
          for (int rt = 0; rt < 2; ++rt)
            acc[rt][ct] = __builtin_amdgcn_mfma_f32_16x16x32_bf16(wf[ks], af[rt][ks],
                                                                  acc[rt][ct], 0, 0, 0);
      }
#pragma unroll
      for (int rt = 0; rt < 2; ++rt) {
        int row = rbase + rt * 16 + l16;
        if (row >= NN) continue;
#pragma unroll
        for (int ct = 0; ct < 8; ++ct) {
          int nc = ct * 16 + g * 4;
          const float4 bb = *(const float4*)(bs + m * HID + nc);
          float o0 = acc[rt][ct][0] + bb.x;
          float o1 = acc[rt][ct][1] + bb.y;
          float o2 = acc[rt][ct][2] + bb.z;
          float o3 = acc[rt][ct][3] + bb.w;
          if (m == 0) {
            u32 lo = (u32)f2b(o0) | ((u32)f2b(o1) << 16);
            u32 hi = (u32)f2b(o2) | ((u32)f2b(o3) << 16);
            *(uint2*)(Oq + (size_t)row * HID + nc) = make_uint2(lo, hi);
          } else {
            u8* O8 = (m == 1) ? Ok : Ov;
            u32 pk = __builtin_amdgcn_cvt_pk_fp8_f32(o0, o1, 0u, false);
            pk = __builtin_amdgcn_cvt_pk_fp8_f32(o2, o3, pk, true);
            *(u32*)(O8 + (size_t)row * HID + nc) = pk;
          }
        }
      }
    }
    if (cn >= QCHUNKS) break;
#pragma unroll
    for (int rt = 0; rt < 2; ++rt)
#pragma unroll
      for (int ks = 0; ks < 4; ++ks) af[rt][ks] = afn[rt][ks];
    c = cn;
  }
}

// ---------------- generic MFMA GEMM (NMAT=1; input/out layers) ----------------
template <int NMAT, bool RELU, bool SKIP, bool FP8KV, bool AF32>
__global__ __launch_bounds__(256) void mfgemm(
    const void* __restrict__ A0, const void* __restrict__ A1, int M, int gb,
    const u16* __restrict__ WT, size_t wtStride,
    const float* __restrict__ bias, size_t biasStride,
    u16* __restrict__ O00, u16* __restrict__ O01, u16* __restrict__ O02,
    u16* __restrict__ O10, u16* __restrict__ O11, u16* __restrict__ O12,
    float* __restrict__ Of0, float* __restrict__ Of1,
    const u16* __restrict__ hp0, const u16* __restrict__ hp1,
    const float* __restrict__ skipP, int resflag) {
  __shared__ __align__(16) u16 sW[HID * HID];
  const int t = blockIdx.x >= gb;
  const int bx = t ? blockIdx.x - gb : blockIdx.x;
  const void* A = t ? A1 : A0;
  const u16* Wg = WT + (size_t)t * wtStride;
  const float* bs = bias + (size_t)t * biasStride;
  u16* Os[3];
  Os[0] = t ? O10 : O00; Os[1] = t ? O11 : O01; Os[2] = t ? O12 : O02;
  float* Of = t ? Of1 : Of0;
  const u16* hprev = t ? hp1 : hp0;

  const int lane = threadIdx.x & 63;
  const int wid = threadIdx.x >> 6;
  const int l16 = lane & 15, g = lane >> 4;
  const int rbase = bx * 128 + wid * 32;

  float beta = 0.f;
  if (SKIP) beta = 1.f / (1.f + __expf(-skipP[t]));

  auto stageW = [&](int m) {
    const u16* Wm = Wg + (size_t)m * HID * HID;
#pragma unroll
    for (int j = 0; j < 8; ++j) {
      int ins = wid * 8 + j;
      int o16 = ins * 64 + lane;
      int row = o16 >> 4, ch = o16 & 15;
      const u16* src = Wm + (size_t)row * HID + ((ch ^ (row & 7)) << 3);
      u16* dst = sW + (size_t)ins * 512;
      __builtin_amdgcn_global_load_lds(
          (const __attribute__((address_space(1))) unsigned int*)src,
          (__attribute__((address_space(3))) unsigned int*)dst, 16, 0, 0);
    }
  };

  bfrag af[2][4];
  int rowA[2];
#pragma unroll
  for (int rt = 0; rt < 2; ++rt) {
    int row = rbase + rt * 16 + l16;
    rowA[rt] = row;
    int rl = row < M ? row : M - 1;
    if (AF32) {
      const float* apf = (const float*)A + (size_t)rl * HID;
#pragma unroll
      for (int ks = 0; ks < 4; ++ks) {
        float4 u0 = *(const float4*)(apf + (ks * 4 + g) * 8);
        float4 u1 = *(const float4*)(apf + (ks * 4 + g) * 8 + 4);
        union { u16 s[8]; bfrag b; } pk;
        pk.s[0] = f2b(u0.x); pk.s[1] = f2b(u0.y); pk.s[2] = f2b(u0.z); pk.s[3] = f2b(u0.w);
        pk.s[4] = f2b(u1.x); pk.s[5] = f2b(u1.y); pk.s[6] = f2b(u1.z); pk.s[7] = f2b(u1.w);
        af[rt][ks] = pk.b;
      }
    } else {
      const bfrag* ap = (const bfrag*)A + (size_t)rl * (HID / 8);
#pragma unroll
      for (int ks = 0; ks < 4; ++ks) af[rt][ks] = ap[ks * 4 + g];
    }
  }

  stageW(0);
  __syncthreads();

#pragma unroll
  for (int m = 0; m < NMAT; ++m) {
    f32x4 acc[2][8];
#pragma unroll
    for (int rt = 0; rt < 2; ++rt)
#pragma unroll
      for (int ct = 0; ct < 8; ++ct) acc[rt][ct] = (f32x4){0.f, 0.f, 0.f, 0.f};
#pragma unroll
    for (int ct = 0; ct < 8; ++ct) {
      int row = ct * 16 + l16;
      bfrag wf[4];
#pragma unroll
      for (int ks = 0; ks < 4; ++ks)
        wf[ks] = *(const bfrag*)&sW[(size_t)row * HID + (((ks * 4 + g) ^ (row & 7)) << 3)];
#pragma unroll
      for (int ks = 0; ks < 4; ++ks)
#pragma unroll
        for (int rt = 0; rt < 2; ++rt)
          acc[rt][ct] = __builtin_amdgcn_mfma_f32_16x16x32_bf16(wf[ks], af[rt][ks],
                                                                acc[rt][ct], 0, 0, 0);
    }
    if (m + 1 < NMAT) {
      __syncthreads();
      stageW(m + 1);
    }
    u16* Ob = Os[m];
#pragma unroll
    for (int rt = 0; rt < 2; ++rt) {
      int row = rowA[rt];
      if (row >= M) continue;
#pragma unroll
      for (int ct = 0; ct < 8; ++ct) {
        int nc = ct * 16 + g * 4;
        const float4 bb = *(const float4*)(bs + m * HID + nc);
        float o0 = acc[rt][ct][0] + bb.x;
        float o1 = acc[rt][ct][1] + bb.y;
        float o2 = acc[rt][ct][2] + bb.z;
        float o3 = acc[rt][ct][3] + bb.w;
        if (RELU) {
          o0 = fmaxf(o0, 0.f); o1 = fmaxf(o1, 0.f);
          o2 = fmaxf(o2, 0.f); o3 = fmaxf(o3, 0.f);
        }
        if (SKIP) {
          uint2 hh2 = *(const uint2*)(hprev + (size_t)row * HID + nc);
          float h0 = b2f(hh2.x << 16), h1 = b2f(hh2.x & 0xFFFF0000u);
          float h2 = b2f(hh2.y << 16), h3 = b2f(hh2.y & 0xFFFF0000u);
          o0 = beta * o0 + (1.f - beta) * h0;
          o1 = beta * o1 + (1.f - beta) * h1;
          o2 = beta * o2 + (1.f - beta) * h2;
          o3 = beta * o3 + (1.f - beta) * h3;
          if (resflag) { o0 += h0; o1 += h1; o2 += h2; o3 += h3; }
        }
        if (FP8KV && m >= 1) {
          u32 pk = __builtin_amdgcn_cvt_pk_fp8_f32(o0, o1, 0u, false);
          pk = __builtin_amdgcn_cvt_pk_fp8_f32(o2, o3, pk, true);
          *(u32*)((u8*)Ob + (size_t)row * HID + nc) = pk;
        } else {
          if (Ob != nullptr) {
            u32 lo = (u32)f2b(o0) | ((u32)f2b(o1) << 16);
            u32 hi = (u32)f2b(o2) | ((u32)f2b(o3) << 16);
            *(uint2*)(Ob + (size_t)row * HID + nc) = make_uint2(lo, hi);
          }
          if (NMAT == 1 && Of != nullptr) {
            *(float4*)(Of + (size_t)row * HID + nc) = make_float4(o0, o1, o2, o3);
          }
        }
      }
    }
    if (m + 1 < NMAT) __syncthreads();
  }
}

// Fused per-(dst,head) attention gather, both relations in one launch.
__global__ __launch_bounds__(256) void agg_csr(
    const int* __restrict__ rp0, const int* __restrict__ ss0, const int* __restrict__ od0,
    const u16* __restrict__ q0, const u8* __restrict__ k0,
    const u8* __restrict__ v0, u16* __restrict__ o0,
    const int* __restrict__ rp1, const int* __restrict__ ss1, const int* __restrict__ od1,
    const u16* __restrict__ q1, const u8* __restrict__ k1,
    const u8* __restrict__ v1, u16* __restrict__ o1, int agb) {
  const int r = blockIdx.x >= agb;
  const int bx = r ? blockIdx.x - agb : blockIdx.x;
  int i = bx * 256 + threadIdx.x;
  if (i >= NN * NH) return;
  const int* rowptr = r ? rp1 : rp0;
  const int* srcs = r ? ss1 : ss0;
  const int* order = r ? od1 : od0;
  const u16* qT = r ? q1 : q0;
  const u8* kT = r ? k1 : k0;
  const u8* vT = r ? v1 : v0;
  u16* aggb = r ? o1 : o0;

  int dst = order[i >> 2], h = i & 3;
  float qv[HD];
  {
    const uint4* qp = (const uint4*)(qT + (size_t)dst * HID + h * HD);
#pragma unroll
    for (int j = 0; j < 4; ++j) up8(qp[j], qv + j * 8);
  }
  float acc[HD];
#pragma unroll
  for (int j = 0; j < HD; ++j) acc[j] = 0.f;
  float z = 0.f;
  int b = rowptr[dst], e2 = rowptr[dst + 1];
  for (int idx = b; idx < e2; ++idx) {
    int src = srcs[idx];
    const uint4* kp = (const uint4*)(kT + (size_t)src * HID + h * HD);
    const uint4* vp = (const uint4*)(vT + (size_t)src * HID + h * HD);
    uint4 ka0 = kp[0], ka1 = kp[1];
    uint4 va0 = vp[0], va1 = vp[1];
    u32 kw[8] = {ka0.x, ka0.y, ka0.z, ka0.w, ka1.x, ka1.y, ka1.z, ka1.w};
    u32 vw[8] = {va0.x, va0.y, va0.z, va0.w, va1.x, va1.y, va1.z, va1.w};
    float s = 0.f;
#pragma unroll
    for (int j = 0; j < 8; ++j) {
      f32x2 p0 = __builtin_amdgcn_cvt_pk_f32_fp8(kw[j], false);
      f32x2 p1 = __builtin_amdgcn_cvt_pk_f32_fp8(kw[j], true);
      s += qv[4 * j] * p0.x + qv[4 * j + 1] * p0.y + qv[4 * j + 2] * p1.x + qv[4 * j + 3] * p1.y;
    }
    s = fminf(s, 60.f);
    float ev = __expf(s);
    z += ev;
#pragma unroll
    for (int j = 0; j < 8; ++j) {
      f32x2 p0 = __builtin_amdgcn_cvt_pk_f32_fp8(vw[j], false);
      f32x2 p1 = __builtin_amdgcn_cvt_pk_f32_fp8(vw[j], true);
      acc[4 * j] += ev * p0.x; acc[4 * j + 1] += ev * p0.y;
      acc[4 * j + 2] += ev * p1.x; acc[4 * j + 3] += ev * p1.y;
    }
  }
  float inv = 1.f / (z + 1e-16f);
  u16* ap = aggb + (size_t)dst * HID + h * HD;
  u32 w[16];
#pragma unroll
  for (int j = 0; j < 16; ++j) {
    float a0 = geluf(acc[2 * j] * inv);
    float a1 = geluf(acc[2 * j + 1] * inv);
    w[j] = (u32)f2b(a0) | ((u32)f2b(a1) << 16);
  }
#pragma unroll
  for (int j = 0; j < 4; ++j)
    *(uint4*)(ap + j * 8) = make_uint4(w[4 * j], w[4 * j + 1], w[4 * j + 2], w[4 * j + 3]);
}

extern "C" void kernel_launch(void* const* d_in, const int* in_sizes, int n_in,
                              void* d_out, int out_size, void* d_ws, size_t ws_size,
                              hipStream_t stream) {
  const float* x_user = (const float*)d_in[0];
  const float* x_item = (const float*)d_in[1];
  const float* W_in = (const float*)d_in[2];
  const float* b_in = (const float*)d_in[3];
  const float* Wk = (const float*)d_in[4];
  const float* bk = (const float*)d_in[5];
  const float* Wq = (const float*)d_in[6];
  const float* bq = (const float*)d_in[7];
  const float* Wv = (const float*)d_in[8];
  const float* bv = (const float*)d_in[9];
  const float* a_rel = (const float*)d_in[10];
  const float* m_rel = (const float*)d_in[11];
  const float* p_rel = (const float*)d_in[12];
  const float* Wo = (const float*)d_in[13];
  const float* bo = (const float*)d_in[14];
  const float* skipP = (const float*)d_in[15];
  const int* edge_ui = (const int*)d_in[16];
  const int* edge_iu = (const int*)d_in[17];
  float* out = (float*)d_out;

  char* p = (char*)d_ws;
  auto take = [&](size_t bytes) {
    void* r = (void*)p;
    p += (bytes + 255) & ~(size_t)255;
    return r;
  };
  size_t nodeB = (size_t)NN * HID * sizeof(u16);
  size_t node8 = (size_t)NN * HID;
  u16* hb[2] = {(u16*)take(nodeB), (u16*)take(nodeB)};         // bf16 h (in-place updated)
  u16* qb[2] = {(u16*)take(nodeB), (u16*)take(nodeB)};         // bf16 q
  u8* kb[2] = {(u8*)take(node8), (u8*)take(node8)};            // fp8 k
  u8* vb[2] = {(u8*)take(node8), (u8*)take(node8)};            // fp8 v
  u16* aggb[2] = {(u16*)take(nodeB), (u16*)take(nodeB)};       // gelu'd agg bf16
  int* deg2   = (int*)take((size_t)2 * NN * 4);
  int* cur2   = (int*)take((size_t)2 * NN * 4);
  int* bsum2  = (int*)take((size_t)2 * NB * 4);
  int* boff2  = (int*)take((size_t)2 * NB * 4);
  int* hist2  = (int*)take((size_t)2 * 64 * 4);
  int* hcur2  = (int*)take((size_t)2 * 64 * 4);
  int* rp2    = (int*)take((size_t)2 * (NN + 1) * 4);
  int* srcs[2]  = {(int*)take((size_t)NE * 4), (int*)take((size_t)NE * 4)};
  int* order[2] = {(int*)take((size_t)NN * 4), (int*)take((size_t)NN * 4)};
  u16* winT  = (u16*)take((size_t)2 * HID * HID * 2);
  u16* woT   = (u16*)take((size_t)4 * HID * HID * 2);
  u16* wqkvT = (u16*)take((size_t)2 * 2 * 3 * HID * HID * 2);  // [l][t][q,k,v]
  float* bqkv = (float*)take((size_t)2 * 2 * 3 * HID * 4);
  size_t used = (size_t)(p - (char*)d_ws);
  if (used > ws_size) {
    fprintf(stderr, "HGT kernel: workspace too small: need %zu, have %zu\n", used, ws_size);
    return;
  }

  const int GB = (NN + 127) / 128;
  const int EB = (NE + 255) / 256;
  const int DB = (NN + 255) / 256;
  dim3 blk(256);

  // ---- CSR build + degree sort (merged across relations) ----
  hipMemsetAsync(deg2, 0, (size_t)2 * NN * 4, stream);
  csr_count<<<dim3(EB, 2), blk, 0, stream>>>(edge_ui, edge_iu, deg2);
  scan1<<<dim3(NB, 2), SCANB, 0, stream>>>(deg2, rp2, bsum2);
  scan2<<<dim3(1, 2), 128, 0, stream>>>(bsum2, boff2);
  scan3<<<dim3(NB, 2), SCANB, 0, stream>>>(rp2, cur2, boff2);
  csr_fill<<<dim3(EB, 2), blk, 0, stream>>>(edge_ui, edge_iu, cur2, srcs[0], srcs[1]);
  hipMemsetAsync(hist2, 0, 2 * 64 * 4, stream);
  hist_deg<<<dim3(DB, 2), blk, 0, stream>>>(rp2, hist2);
  scan_hist<<<dim3(1, 2), 64, 0, stream>>>(hist2, hcur2);
  scatter_deg<<<dim3(DB, 2), blk, 0, stream>>>(rp2, hcur2, order[0], order[1]);
  int* rowptr[2] = {rp2, rp2 + (NN + 1)};

  // ---- weight prep (all upfront, wide grids) ----
  prep_wT<<<dim3(64, 2), blk, 0, stream>>>(W_in, HID * HID, winT, HID * HID,
                                           nullptr, 0, nullptr, 0, nullptr);
  prep_wT<<<dim3(64, 4), blk, 0, stream>>>(Wo, HID * HID, woT, HID * HID,
                                           nullptr, 0, nullptr, 0, nullptr);
  prep_wT<<<dim3(64, 4), blk, 0, stream>>>(Wq, HID * HID, wqkvT, 3 * HID * HID,
                                           bq, HID, bqkv, 3 * HID, p_rel);
  combine_all<<<dim3(64, 4, 2), blk, 0, stream>>>(Wk, bk, Wv, bv, a_rel, m_rel,
                                                  wqkvT, bqkv);

  // ---- input linear + relu (x fp32 read directly; h written bf16 only) ----
  mfgemm<1, true, false, false, true><<<2 * GB, blk, 0, stream>>>(
      x_user, x_item, NN, GB, winT, HID * HID, b_in, HID,
      hb[0], nullptr, nullptr, hb[1], nullptr, nullptr,
      nullptr, nullptr, nullptr, nullptr, nullptr, 0);

  const int AGB = (NN * NH + 255) / 256;
  for (int l = 0; l < LL; ++l) {
    // q/k/v projections: 8-wave blocks, 96KB LDS, one barrier, chunk loop + prefetch
    qkv_gemm<<<2 * QSLOT, dim3(512), 0, stream>>>(
        hb[0], hb[1],
        wqkvT + (size_t)l * 2 * 3 * HID * HID,
        bqkv + (size_t)l * 2 * 3 * HID,
        qb[0], qb[1], kb[0], kb[1], vb[0], vb[1]);
    // attention gather, both relations (r: st=r, dt=1-r)
    agg_csr<<<2 * AGB, blk, 0, stream>>>(
        rowptr[0], srcs[0], order[0], qb[1], kb[0], vb[0], aggb[1],
        rowptr[1], srcs[1], order[1], qb[0], kb[1], vb[1], aggb[0], AGB);
    // output linear + skip: l=0 -> new h bf16 into hb; l=1 -> fp32 d_out only
    if (l == 0) {
      mfgemm<1, false, true, false, false><<<2 * GB, blk, 0, stream>>>(
          aggb[0], aggb[1], NN, GB,
          woT, HID * HID, bo, HID,
          hb[0], nullptr, nullptr, hb[1], nullptr, nullptr,
          nullptr, nullptr, hb[0], hb[1], skipP, 0);
    } else {
      mfgemm<1, false, true, false, false><<<2 * GB, blk, 0, stream>>>(
          aggb[0], aggb[1], NN, GB,
          woT + (size_t)2 * HID * HID, HID * HID, bo + 2 * HID, HID,
          nullptr, nullptr, nullptr, nullptr, nullptr, nullptr,
          out, out + (size_t)NN * HID, hb[0], hb[1], skipP + 2, 1);
    }
  }
}

// Round 14
// 794.696 us; speedup vs baseline: 1.0424x; 1.0424x over previous
//
#include <hip/hip_runtime.h>
#include <stdint.h>
#include <stdio.h>

#define NN 100000
#define NE 500000
#define HID 128
#define NH 4
#define HD 32
#define LL 2
#define SCANB 1024
#define NB ((NN + SCANB - 1) / SCANB)
#define QBLK 128                    // blocks per type in qkv_gemm (1 block/CU total)
#define QCH256 ((NN + 255) / 256)   // 391 chunks of 256 rows

typedef unsigned short u16;
typedef unsigned char u8;
typedef unsigned int u32;
typedef __attribute__((ext_vector_type(8))) short bfrag;   // 8 bf16 = 4 VGPR
typedef __attribute__((ext_vector_type(4))) float f32x4;
typedef __attribute__((ext_vector_type(2))) float f32x2;

__device__ __forceinline__ float b2f(u32 lo16) {
  union { u32 u; float f; } c; c.u = lo16; return c.f;
}
__device__ __forceinline__ u16 f2b(float f) {
  union { float f; u32 u; } c; c.f = f;
  u32 u = c.u;
  u32 r = (u + 0x7FFFu + ((u >> 16) & 1u)) >> 16;
  return (u16)r;
}
__device__ __forceinline__ float geluf(float x) {
  return 0.5f * x * (1.0f + erff(x * 0.70710678118654752f));
}
__device__ __forceinline__ void up8(uint4 a, float* f) {
  f[0] = b2f(a.x << 16); f[1] = b2f(a.x & 0xFFFF0000u);
  f[2] = b2f(a.y << 16); f[3] = b2f(a.y & 0xFFFF0000u);
  f[4] = b2f(a.z << 16); f[5] = b2f(a.z & 0xFFFF0000u);
  f[6] = b2f(a.w << 16); f[7] = b2f(a.w & 0xFFFF0000u);
}

// ---------------- CSR build (both relations in one launch, blockIdx.y = r) ----
__global__ __launch_bounds__(256) void csr_count(const int* __restrict__ e0,
                                                 const int* __restrict__ e1,
                                                 int* __restrict__ deg) {
  int r = blockIdx.y;
  const int* edges = r ? e1 : e0;
  int e = blockIdx.x * 256 + threadIdx.x;
  if (e < NE) atomicAdd(&deg[(size_t)r * NN + edges[NE + e]], 1);
}

__global__ __launch_bounds__(SCANB) void scan1(const int* __restrict__ deg,
                                               int* __restrict__ rp,
                                               int* __restrict__ bsum) {
  __shared__ int ls[SCANB];
  int r = blockIdx.y;
  int t = threadIdx.x;
  int g = blockIdx.x * SCANB + t;
  int v = (g < NN) ? deg[(size_t)r * NN + g] : 0;
  ls[t] = v;
  __syncthreads();
#pragma unroll
  for (int off = 1; off < SCANB; off <<= 1) {
    int u = (t >= off) ? ls[t - off] : 0;
    __syncthreads();
    ls[t] += u;
    __syncthreads();
  }
  if (g < NN) rp[(size_t)r * (NN + 1) + g] = ls[t] - v;
  if (t == SCANB - 1) bsum[r * NB + blockIdx.x] = ls[t];
}

__global__ __launch_bounds__(128) void scan2(const int* __restrict__ bsum,
                                             int* __restrict__ boff) {
  __shared__ int ls[128];
  int r = blockIdx.y;
  int t = threadIdx.x;
  int v = (t < NB) ? bsum[r * NB + t] : 0;
  ls[t] = v;
  __syncthreads();
#pragma unroll
  for (int off = 1; off < 128; off <<= 1) {
    int u = (t >= off) ? ls[t - off] : 0;
    __syncthreads();
    ls[t] += u;
    __syncthreads();
  }
  if (t < NB) boff[r * NB + t] = ls[t] - v;
}

__global__ __launch_bounds__(SCANB) void scan3(int* __restrict__ rp,
                                               int* __restrict__ cursor,
                                               const int* __restrict__ boff) {
  int r = blockIdx.y;
  int g = blockIdx.x * SCANB + threadIdx.x;
  if (g < NN) {
    int v = rp[(size_t)r * (NN + 1) + g] + boff[r * NB + blockIdx.x];
    rp[(size_t)r * (NN + 1) + g] = v;
    cursor[(size_t)r * NN + g] = v;
  }
  if (g == 0) rp[(size_t)r * (NN + 1) + NN] = NE;
}

__global__ __launch_bounds__(256) void csr_fill(const int* __restrict__ e0,
                                                const int* __restrict__ e1,
                                                int* __restrict__ cursor,
                                                int* __restrict__ s0,
                                                int* __restrict__ s1) {
  int r = blockIdx.y;
  const int* edges = r ? e1 : e0;
  int* srcs = r ? s1 : s0;
  int e = blockIdx.x * 256 + threadIdx.x;
  if (e < NE) {
    int pos = atomicAdd(&cursor[(size_t)r * NN + edges[NE + e]], 1);
    srcs[pos] = edges[e];
  }
}

// ---------------- degree sort (two-level counting sort, keys 0..63) ----------------
__global__ __launch_bounds__(256) void hist_deg(const int* __restrict__ rp,
                                                int* __restrict__ hist) {
  __shared__ int lh[64];
  int r = blockIdx.y;
  if (threadIdx.x < 64) lh[threadIdx.x] = 0;
  __syncthreads();
  int d = blockIdx.x * 256 + threadIdx.x;
  if (d < NN) {
    const int* rowptr = rp + (size_t)r * (NN + 1);
    int dg = rowptr[d + 1] - rowptr[d];
    atomicAdd(&lh[dg < 63 ? dg : 63], 1);
  }
  __syncthreads();
  if (threadIdx.x < 64 && lh[threadIdx.x])
    atomicAdd(&hist[r * 64 + threadIdx.x], lh[threadIdx.x]);
}

__global__ __launch_bounds__(64) void scan_hist(const int* __restrict__ hist,
                                                int* __restrict__ hcur) {
  __shared__ int ls[64];
  int r = blockIdx.y;
  int t = threadIdx.x;
  int v = hist[r * 64 + t];
  ls[t] = v;
  __syncthreads();
#pragma unroll
  for (int off = 1; off < 64; off <<= 1) {
    int u = (t >= off) ? ls[t - off] : 0;
    __syncthreads();
    ls[t] += u;
    __syncthreads();
  }
  hcur[r * 64 + t] = ls[t] - v;
}

__global__ __launch_bounds__(256) void scatter_deg(const int* __restrict__ rp,
                                                   int* __restrict__ hcur,
                                                   int* __restrict__ o0,
                                                   int* __restrict__ o1) {
  __shared__ int lh[64];
  __shared__ int lbase[64];
  int r = blockIdx.y;
  int* order = r ? o1 : o0;
  if (threadIdx.x < 64) lh[threadIdx.x] = 0;
  __syncthreads();
  int d = blockIdx.x * 256 + threadIdx.x;
  int dg = 0, rank = 0;
  if (d < NN) {
    const int* rowptr = rp + (size_t)r * (NN + 1);
    dg = rowptr[d + 1] - rowptr[d];
    if (dg > 63) dg = 63;
    rank = atomicAdd(&lh[dg], 1);
  }
  __syncthreads();
  if (threadIdx.x < 64)
    lbase[threadIdx.x] = lh[threadIdx.x] ? atomicAdd(&hcur[r * 64 + threadIdx.x], lh[threadIdx.x]) : 0;
  __syncthreads();
  if (d < NN) order[lbase[dg] + rank] = d;
}

// ---------------- weight prep ----------------
__global__ __launch_bounds__(256) void prep_wT(const float* __restrict__ src, size_t srcStride,
                                               u16* __restrict__ dst, size_t dstStride,
                                               const float* __restrict__ bsrc, int bsStride,
                                               float* __restrict__ bdst, int bdStride,
                                               const float* __restrict__ p_rel_q) {
  int m = blockIdx.y;
  const float* S = src + (size_t)m * srcStride;
  u16* D = dst + (size_t)m * dstStride;
  int idx = blockIdx.x * 256 + threadIdx.x;
  int k = idx >> 7, n = idx & 127;
  float v = S[idx];
  if (p_rel_q != nullptr) {
    int l = m >> 1, t = m & 1;
    v *= p_rel_q[((l << 1) | (1 - t)) * NH + (n >> 5)] * 0.17677669529663687f;
  }
  D[(size_t)n * HID + k] = f2b(v);
  if (bsrc != nullptr && blockIdx.x == 0 && threadIdx.x < HID) {
    int col = threadIdx.x;
    float bvv = bsrc[(size_t)m * bsStride + col];
    if (p_rel_q != nullptr) {
      int l = m >> 1, t = m & 1;
      bvv *= p_rel_q[((l << 1) | (1 - t)) * NH + (col >> 5)] * 0.17677669529663687f;
    }
    bdst[(size_t)m * bdStride + col] = bvv;
  }
}

__global__ __launch_bounds__(256) void combine_all(
    const float* __restrict__ Wk, const float* __restrict__ bk,
    const float* __restrict__ Wv, const float* __restrict__ bv,
    const float* __restrict__ a_rel, const float* __restrict__ m_rel,
    u16* __restrict__ wqkvT, float* __restrict__ bqkv) {
  int l = blockIdx.z;
  int t = blockIdx.y >> 1, which = blockIdx.y & 1;
  const float* W  = (which == 0 ? Wk : Wv) + (size_t)(l * 2 + t) * HID * HID;
  const float* b  = (which == 0 ? bk : bv) + (size_t)(l * 2 + t) * HID;
  const float* Ar = (which == 0 ? a_rel : m_rel) + (size_t)(l * 2 + t) * NH * HD * HD;
  u16* Wd = wqkvT + ((size_t)(l * 2 + t) * 3 + 1 + which) * HID * HID;
  float* bd = bqkv + ((size_t)(l * 2 + t) * 3 + 1 + which) * HID;
  int idx = blockIdx.x * 256 + threadIdx.x;
  int i = idx >> 7, col = idx & 127;
  int h = col >> 5, e = col & 31;
  {
    const float* ap = Ar + h * HD * HD + e;
    const float* wp = W + (size_t)i * HID + h * HD;
    float s = 0.f;
#pragma unroll
    for (int d = 0; d < HD; ++d) s += wp[d] * ap[d * HD];
    Wd[(size_t)col * HID + i] = f2b(s);
  }
  if (blockIdx.x == 0 && threadIdx.x < HID) {
    int col2 = threadIdx.x, h2 = col2 >> 5, e2 = col2 & 31;
    const float* ap = Ar + h2 * HD * HD + e2;
    const float* bp = b + h2 * HD;
    float s = 0.f;
#pragma unroll
    for (int d = 0; d < HD; ++d) s += bp[d] * ap[d * HD];
    bd[col2] = s;
  }
}

// ---------------- qkv GEMM: 8 waves, 96KB LDS, one barrier, chunk loop (no prefetch) --
// grid = 2*QBLK blocks of 512 threads (1 block/CU). Block handles chunks
// c = slot, slot+QBLK, ... of 256 rows (8 waves x 32 rows). LDS read-only after barrier.
__global__ __launch_bounds__(512, 1) void qkv_gemm(
    const u16* __restrict__ h0, const u16* __restrict__ h1,
    const u16* __restrict__ WT,      // [t][3][n][k] bf16 (layer slice)
    const float* __restrict__ bias,  // [t][3][128]  (layer slice)
    u16* __restrict__ q0, u16* __restrict__ q1,
    u8* __restrict__ k0, u8* __restrict__ k1,
    u8* __restrict__ v0, u8* __restrict__ v1) {
  __shared__ __align__(16) u16 sW[3 * HID * HID];   // 96 KB: q,k,v weights
  const int t = blockIdx.x >= QBLK;
  const int slot = t ? blockIdx.x - QBLK : blockIdx.x;
  const u16* A = t ? h1 : h0;
  const u16* Wg = WT + (size_t)t * 3 * HID * HID;
  const float* bs = bias + (size_t)t * 3 * HID;
  u16* Oq = t ? q1 : q0;
  u8* Ok = t ? k1 : k0;
  u8* Ov = t ? v1 : v0;

  const int lane = threadIdx.x & 63;
  const int wid = threadIdx.x >> 6;          // 0..7
  const int l16 = lane & 15, g = lane >> 4;

  // ---- stage all 3 mats: 96 instrs over 8 waves (linear dest, inv-swizzled src) ----
#pragma unroll
  for (int m = 0; m < 3; ++m) {
#pragma unroll
    for (int j = 0; j < 4; ++j) {
      int ins = wid * 4 + j;                  // 0..31 within mat
      int o16 = ins * 64 + lane;
      int row = o16 >> 4, ch = o16 & 15;
      const u16* src = Wg + (size_t)m * HID * HID + (size_t)row * HID + ((ch ^ (row & 7)) << 3);
      u16* dst = sW + (size_t)m * HID * HID + (size_t)ins * 512;
      __builtin_amdgcn_global_load_lds(
          (const __attribute__((address_space(1))) unsigned int*)src,
          (__attribute__((address_space(3))) unsigned int*)dst, 16, 0, 0);
    }
  }
  __syncthreads();   // the ONLY barrier

  for (int c = slot; c < QCH256; c += QBLK) {
    const int rbase = c * 256 + wid * 32;
    bfrag af[2][4];
#pragma unroll
    for (int rt = 0; rt < 2; ++rt) {
      int row = rbase + rt * 16 + l16;
      int rl = row < NN ? row : NN - 1;
      const bfrag* ap = (const bfrag*)(A + (size_t)rl * HID);
#pragma unroll
      for (int ks = 0; ks < 4; ++ks) af[rt][ks] = ap[ks * 4 + g];
    }

#pragma unroll
    for (int m = 0; m < 3; ++m) {
      f32x4 acc[2][8];
#pragma unroll
      for (int rt = 0; rt < 2; ++rt)
#pragma unroll
        for (int ct = 0; ct < 8; ++ct) acc[rt][ct] = (f32x4){0.f, 0.f, 0.f, 0.f};
#pragma unroll
      for (int ct = 0; ct < 8; ++ct) {
        int row = ct * 16 + l16;
        bfrag wf[4];
#pragma unroll
        for (int ks = 0; ks < 4; ++ks)
          wf[ks] = *(const bfrag*)&sW[(size_t)m * HID * HID + (size_t)row * HID +
                                      (((ks * 4 + g) ^ (row & 7)) << 3)];
#pragma unroll
        for (int ks = 0; ks < 4; ++ks)
#pragma unroll
          for (int rt = 0; rt < 2; ++rt)
            acc[rt][ct] = __builtin_amdgcn_mfma_f32_16x16x32_bf16(wf[ks], af[rt][ks],
                                                                  acc[rt][ct], 0, 0, 0);
      }
#pragma unroll
      for (int rt = 0; rt < 2; ++rt) {
        int row = rbase + rt * 16 + l16;
        if (row >= NN) continue;
#pragma unroll
        for (int ct = 0; ct < 8; ++ct) {
          int nc = ct * 16 + g * 4;
          const float4 bb = *(const float4*)(bs + m * HID + nc);
          float o0 = acc[rt][ct][0] + bb.x;
          float o1 = acc[rt][ct][1] + bb.y;
          float o2 = acc[rt][ct][2] + bb.z;
          float o3 = acc[rt][ct][3] + bb.w;
          if (m == 0) {
            u32 lo = (u32)f2b(o0) | ((u32)f2b(o1) << 16);
            u32 hi = (u32)f2b(o2) | ((u32)f2b(o3) << 16);
            *(uint2*)(Oq + (size_t)row * HID + nc) = make_uint2(lo, hi);
          } else {
            u8* O8 = (m == 1) ? Ok : Ov;
            u32 pk = __builtin_amdgcn_cvt_pk_fp8_f32(o0, o1, 0u, false);
            pk = __builtin_amdgcn_cvt_pk_fp8_f32(o2, o3, pk, true);
            *(u32*)(O8 + (size_t)row * HID + nc) = pk;
          }
        }
      }
    }
  }
}

// ---------------- generic MFMA GEMM (NMAT=1; input/out layers) ----------------
template <int NMAT, bool RELU, bool SKIP, bool FP8KV, bool AF32>
__global__ __launch_bounds__(256) void mfgemm(
    const void* __restrict__ A0, const void* __restrict__ A1, int M, int gb,
    const u16* __restrict__ WT, size_t wtStride,
    const float* __restrict__ bias, size_t biasStride,
    u16* __restrict__ O00, u16* __restrict__ O01, u16* __restrict__ O02,
    u16* __restrict__ O10, u16* __restrict__ O11, u16* __restrict__ O12,
    float* __restrict__ Of0, float* __restrict__ Of1,
    const u16* __restrict__ hp0, const u16* __restrict__ hp1,
    const float* __restrict__ skipP, int resflag) {
  __shared__ __align__(16) u16 sW[HID * HID];
  const int t = blockIdx.x >= gb;
  const int bx = t ? blockIdx.x - gb : blockIdx.x;
  const void* A = t ? A1 : A0;
  const u16* Wg = WT + (size_t)t * wtStride;
  const float* bs = bias + (size_t)t * biasStride;
  u16* Os[3];
  Os[0] = t ? O10 : O00; Os[1] = t ? O11 : O01; Os[2] = t ? O12 : O02;
  float* Of = t ? Of1 : Of0;
  const u16* hprev = t ? hp1 : hp0;

  const int lane = threadIdx.x & 63;
  const int wid = threadIdx.x >> 6;
  const int l16 = lane & 15, g = lane >> 4;
  const int rbase = bx * 128 + wid * 32;

  float beta = 0.f;
  if (SKIP) beta = 1.f / (1.f + __expf(-skipP[t]));

  auto stageW = [&](int m) {
    const u16* Wm = Wg + (size_t)m * HID * HID;
#pragma unroll
    for (int j = 0; j < 8; ++j) {
      int ins = wid * 8 + j;
      int o16 = ins * 64 + lane;
      int row = o16 >> 4, ch = o16 & 15;
      const u16* src = Wm + (size_t)row * HID + ((ch ^ (row & 7)) << 3);
      u16* dst = sW + (size_t)ins * 512;
      __builtin_amdgcn_global_load_lds(
          (const __attribute__((address_space(1))) unsigned int*)src,
          (__attribute__((address_space(3))) unsigned int*)dst, 16, 0, 0);
    }
  };

  bfrag af[2][4];
  int rowA[2];
#pragma unroll
  for (int rt = 0; rt < 2; ++rt) {
    int row = rbase + rt * 16 + l16;
    rowA[rt] = row;
    int rl = row < M ? row : M - 1;
    if (AF32) {
      const float* apf = (const float*)A + (size_t)rl * HID;
#pragma unroll
      for (int ks = 0; ks < 4; ++ks) {
        float4 u0 = *(const float4*)(apf + (ks * 4 + g) * 8);
        float4 u1 = *(const float4*)(apf + (ks * 4 + g) * 8 + 4);
        union { u16 s[8]; bfrag b; } pk;
        pk.s[0] = f2b(u0.x); pk.s[1] = f2b(u0.y); pk.s[2] = f2b(u0.z); pk.s[3] = f2b(u0.w);
        pk.s[4] = f2b(u1.x); pk.s[5] = f2b(u1.y); pk.s[6] = f2b(u1.z); pk.s[7] = f2b(u1.w);
        af[rt][ks] = pk.b;
      }
    } else {
      const bfrag* ap = (const bfrag*)A + (size_t)rl * (HID / 8);
#pragma unroll
      for (int ks = 0; ks < 4; ++ks) af[rt][ks] = ap[ks * 4 + g];
    }
  }

  stageW(0);
  __syncthreads();

#pragma unroll
  for (int m = 0; m < NMAT; ++m) {
    f32x4 acc[2][8];
#pragma unroll
    for (int rt = 0; rt < 2; ++rt)
#pragma unroll
      for (int ct = 0; ct < 8; ++ct) acc[rt][ct] = (f32x4){0.f, 0.f, 0.f, 0.f};
#pragma unroll
    for (int ct = 0; ct < 8; ++ct) {
      int row = ct * 16 + l16;
      bfrag wf[4];
#pragma unroll
      for (int ks = 0; ks < 4; ++ks)
        wf[ks] = *(const bfrag*)&sW[(size_t)row * HID + (((ks * 4 + g) ^ (row & 7)) << 3)];
#pragma unroll
      for (int ks = 0; ks < 4; ++ks)
#pragma unroll
        for (int rt = 0; rt < 2; ++rt)
          acc[rt][ct] = __builtin_amdgcn_mfma_f32_16x16x32_bf16(wf[ks], af[rt][ks],
                                                                acc[rt][ct], 0, 0, 0);
    }
    if (m + 1 < NMAT) {
      __syncthreads();
      stageW(m + 1);
    }
    u16* Ob = Os[m];
#pragma unroll
    for (int rt = 0; rt < 2; ++rt) {
      int row = rowA[rt];
      if (row >= M) continue;
#pragma unroll
      for (int ct = 0; ct < 8; ++ct) {
        int nc = ct * 16 + g * 4;
        const float4 bb = *(const float4*)(bs + m * HID + nc);
        float o0 = acc[rt][ct][0] + bb.x;
        float o1 = acc[rt][ct][1] + bb.y;
        float o2 = acc[rt][ct][2] + bb.z;
        float o3 = acc[rt][ct][3] + bb.w;
        if (RELU) {
          o0 = fmaxf(o0, 0.f); o1 = fmaxf(o1, 0.f);
          o2 = fmaxf(o2, 0.f); o3 = fmaxf(o3, 0.f);
        }
        if (SKIP) {
          uint2 hh2 = *(const uint2*)(hprev + (size_t)row * HID + nc);
          float h0 = b2f(hh2.x << 16), h1 = b2f(hh2.x & 0xFFFF0000u);
          float h2 = b2f(hh2.y << 16), h3 = b2f(hh2.y & 0xFFFF0000u);
          o0 = beta * o0 + (1.f - beta) * h0;
          o1 = beta * o1 + (1.f - beta) * h1;
          o2 = beta * o2 + (1.f - beta) * h2;
          o3 = beta * o3 + (1.f - beta) * h3;
          if (resflag) { o0 += h0; o1 += h1; o2 += h2; o3 += h3; }
        }
        if (FP8KV && m >= 1) {
          u32 pk = __builtin_amdgcn_cvt_pk_fp8_f32(o0, o1, 0u, false);
          pk = __builtin_amdgcn_cvt_pk_fp8_f32(o2, o3, pk, true);
          *(u32*)((u8*)Ob + (size_t)row * HID + nc) = pk;
        } else {
          if (Ob != nullptr) {
            u32 lo = (u32)f2b(o0) | ((u32)f2b(o1) << 16);
            u32 hi = (u32)f2b(o2) | ((u32)f2b(o3) << 16);
            *(uint2*)(Ob + (size_t)row * HID + nc) = make_uint2(lo, hi);
          }
          if (NMAT == 1 && Of != nullptr) {
            *(float4*)(Of + (size_t)row * HID + nc) = make_float4(o0, o1, o2, o3);
          }
        }
      }
    }
    if (m + 1 < NMAT) __syncthreads();
  }
}

// Fused per-(dst,head) attention gather, both relations in one launch.
__global__ __launch_bounds__(256) void agg_csr(
    const int* __restrict__ rp0, const int* __restrict__ ss0, const int* __restrict__ od0,
    const u16* __restrict__ q0, const u8* __restrict__ k0,
    const u8* __restrict__ v0, u16* __restrict__ o0,
    const int* __restrict__ rp1, const int* __restrict__ ss1, const int* __restrict__ od1,
    const u16* __restrict__ q1, const u8* __restrict__ k1,
    const u8* __restrict__ v1, u16* __restrict__ o1, int agb) {
  const int r = blockIdx.x >= agb;
  const int bx = r ? blockIdx.x - agb : blockIdx.x;
  int i = bx * 256 + threadIdx.x;
  if (i >= NN * NH) return;
  const int* rowptr = r ? rp1 : rp0;
  const int* srcs = r ? ss1 : ss0;
  const int* order = r ? od1 : od0;
  const u16* qT = r ? q1 : q0;
  const u8* kT = r ? k1 : k0;
  const u8* vT = r ? v1 : v0;
  u16* aggb = r ? o1 : o0;

  int dst = order[i >> 2], h = i & 3;
  float qv[HD];
  {
    const uint4* qp = (const uint4*)(qT + (size_t)dst * HID + h * HD);
#pragma unroll
    for (int j = 0; j < 4; ++j) up8(qp[j], qv + j * 8);
  }
  float acc[HD];
#pragma unroll
  for (int j = 0; j < HD; ++j) acc[j] = 0.f;
  float z = 0.f;
  int b = rowptr[dst], e2 = rowptr[dst + 1];
  for (int idx = b; idx < e2; ++idx) {
    int src = srcs[idx];
    const uint4* kp = (const uint4*)(kT + (size_t)src * HID + h * HD);
    const uint4* vp = (const uint4*)(vT + (size_t)src * HID + h * HD);
    uint4 ka0 = kp[0], ka1 = kp[1];
    uint4 va0 = vp[0], va1 = vp[1];
    u32 kw[8] = {ka0.x, ka0.y, ka0.z, ka0.w, ka1.x, ka1.y, ka1.z, ka1.w};
    u32 vw[8] = {va0.x, va0.y, va0.z, va0.w, va1.x, va1.y, va1.z, va1.w};
    float s = 0.f;
#pragma unroll
    for (int j = 0; j < 8; ++j) {
      f32x2 p0 = __builtin_amdgcn_cvt_pk_f32_fp8(kw[j], false);
      f32x2 p1 = __builtin_amdgcn_cvt_pk_f32_fp8(kw[j], true);
      s += qv[4 * j] * p0.x + qv[4 * j + 1] * p0.y + qv[4 * j + 2] * p1.x + qv[4 * j + 3] * p1.y;
    }
    s = fminf(s, 60.f);
    float ev = __expf(s);
    z += ev;
#pragma unroll
    for (int j = 0; j < 8; ++j) {
      f32x2 p0 = __builtin_amdgcn_cvt_pk_f32_fp8(vw[j], false);
      f32x2 p1 = __builtin_amdgcn_cvt_pk_f32_fp8(vw[j], true);
      acc[4 * j] += ev * p0.x; acc[4 * j + 1] += ev * p0.y;
      acc[4 * j + 2] += ev * p1.x; acc[4 * j + 3] += ev * p1.y;
    }
  }
  float inv = 1.f / (z + 1e-16f);
  u16* ap = aggb + (size_t)dst * HID + h * HD;
  u32 w[16];
#pragma unroll
  for (int j = 0; j < 16; ++j) {
    float a0 = geluf(acc[2 * j] * inv);
    float a1 = geluf(acc[2 * j + 1] * inv);
    w[j] = (u32)f2b(a0) | ((u32)f2b(a1) << 16);
  }
#pragma unroll
  for (int j = 0; j < 4; ++j)
    *(uint4*)(ap + j * 8) = make_uint4(w[4 * j], w[4 * j + 1], w[4 * j + 2], w[4 * j + 3]);
}

extern "C" void kernel_launch(void* const* d_in, const int* in_sizes, int n_in,
                              void* d_out, int out_size, void* d_ws, size_t ws_size,
                              hipStream_t stream) {
  const float* x_user = (const float*)d_in[0];
  const float* x_item = (const float*)d_in[1];
  const float* W_in = (const float*)d_in[2];
  const float* b_in = (const float*)d_in[3];
  const float* Wk = (const float*)d_in[4];
  const float* bk = (const float*)d_in[5];
  const float* Wq = (const float*)d_in[6];
  const float* bq = (const float*)d_in[7];
  const float* Wv = (const float*)d_in[8];
  const float* bv = (const float*)d_in[9];
  const float* a_rel = (const float*)d_in[10];
  const float* m_rel = (const float*)d_in[11];
  const float* p_rel = (const float*)d_in[12];
  const float* Wo = (const float*)d_in[13];
  const float* bo = (const float*)d_in[14];
  const float* skipP = (const float*)d_in[15];
  const int* edge_ui = (const int*)d_in[16];
  const int* edge_iu = (const int*)d_in[17];
  float* out = (float*)d_out;

  char* p = (char*)d_ws;
  auto take = [&](size_t bytes) {
    void* r = (void*)p;
    p += (bytes + 255) & ~(size_t)255;
    return r;
  };
  size_t nodeB = (size_t)NN * HID * sizeof(u16);
  size_t node8 = (size_t)NN * HID;
  u16* hb[2] = {(u16*)take(nodeB), (u16*)take(nodeB)};         // bf16 h (in-place updated)
  u16* qb[2] = {(u16*)take(nodeB), (u16*)take(nodeB)};         // bf16 q
  u8* kb[2] = {(u8*)take(node8), (u8*)take(node8)};            // fp8 k
  u8* vb[2] = {(u8*)take(node8), (u8*)take(node8)};            // fp8 v
  u16* aggb[2] = {(u16*)take(nodeB), (u16*)take(nodeB)};       // gelu'd agg bf16
  int* deg2   = (int*)take((size_t)2 * NN * 4);
  int* cur2   = (int*)take((size_t)2 * NN * 4);
  int* bsum2  = (int*)take((size_t)2 * NB * 4);
  int* boff2  = (int*)take((size_t)2 * NB * 4);
  int* hist2  = (int*)take((size_t)2 * 64 * 4);
  int* hcur2  = (int*)take((size_t)2 * 64 * 4);
  int* rp2    = (int*)take((size_t)2 * (NN + 1) * 4);
  int* srcs[2]  = {(int*)take((size_t)NE * 4), (int*)take((size_t)NE * 4)};
  int* order[2] = {(int*)take((size_t)NN * 4), (int*)take((size_t)NN * 4)};
  u16* winT  = (u16*)take((size_t)2 * HID * HID * 2);
  u16* woT   = (u16*)take((size_t)4 * HID * HID * 2);
  u16* wqkvT = (u16*)take((size_t)2 * 2 * 3 * HID * HID * 2);  // [l][t][q,k,v]
  float* bqkv = (float*)take((size_t)2 * 2 * 3 * HID * 4);
  size_t used = (size_t)(p - (char*)d_ws);
  if (used > ws_size) {
    fprintf(stderr, "HGT kernel: workspace too small: need %zu, have %zu\n", used, ws_size);
    return;
  }

  const int GB = (NN + 127) / 128;
  const int EB = (NE + 255) / 256;
  const int DB = (NN + 255) / 256;
  dim3 blk(256);

  // ---- CSR build + degree sort (merged across relations) ----
  hipMemsetAsync(deg2, 0, (size_t)2 * NN * 4, stream);
  csr_count<<<dim3(EB, 2), blk, 0, stream>>>(edge_ui, edge_iu, deg2);
  scan1<<<dim3(NB, 2), SCANB, 0, stream>>>(deg2, rp2, bsum2);
  scan2<<<dim3(1, 2), 128, 0, stream>>>(bsum2, boff2);
  scan3<<<dim3(NB, 2), SCANB, 0, stream>>>(rp2, cur2, boff2);
  csr_fill<<<dim3(EB, 2), blk, 0, stream>>>(edge_ui, edge_iu, cur2, srcs[0], srcs[1]);
  hipMemsetAsync(hist2, 0, 2 * 64 * 4, stream);
  hist_deg<<<dim3(DB, 2), blk, 0, stream>>>(rp2, hist2);
  scan_hist<<<dim3(1, 2), 64, 0, stream>>>(hist2, hcur2);
  scatter_deg<<<dim3(DB, 2), blk, 0, stream>>>(rp2, hcur2, order[0], order[1]);
  int* rowptr[2] = {rp2, rp2 + (NN + 1)};

  // ---- weight prep (all upfront, wide grids) ----
  prep_wT<<<dim3(64, 2), blk, 0, stream>>>(W_in, HID * HID, winT, HID * HID,
                                           nullptr, 0, nullptr, 0, nullptr);
  prep_wT<<<dim3(64, 4), blk, 0, stream>>>(Wo, HID * HID, woT, HID * HID,
                                           nullptr, 0, nullptr, 0, nullptr);
  prep_wT<<<dim3(64, 4), blk, 0, stream>>>(Wq, HID * HID, wqkvT, 3 * HID * HID,
                                           bq, HID, bqkv, 3 * HID, p_rel);
  combine_all<<<dim3(64, 4, 2), blk, 0, stream>>>(Wk, bk, Wv, bv, a_rel, m_rel,
                                                  wqkvT, bqkv);

  // ---- input linear + relu (x fp32 read directly; h written bf16 only) ----
  mfgemm<1, true, false, false, true><<<2 * GB, blk, 0, stream>>>(
      x_user, x_item, NN, GB, winT, HID * HID, b_in, HID,
      hb[0], nullptr, nullptr, hb[1], nullptr, nullptr,
      nullptr, nullptr, nullptr, nullptr, nullptr, 0);

  const int AGB = (NN * NH + 255) / 256;
  for (int l = 0; l < LL; ++l) {
    // q/k/v projections: 8-wave blocks, 96KB LDS, one barrier, chunk loop (no prefetch)
    qkv_gemm<<<2 * QBLK, dim3(512), 0, stream>>>(
        hb[0], hb[1],
        wqkvT + (size_t)l * 2 * 3 * HID * HID,
        bqkv + (size_t)l * 2 * 3 * HID,
        qb[0], qb[1], kb[0], kb[1], vb[0], vb[1]);
    // attention gather, both relations (r: st=r, dt=1-r)
    agg_csr<<<2 * AGB, blk, 0, stream>>>(
        rowptr[0], srcs[0], order[0], qb[1], kb[0], vb[0], aggb[1],
        rowptr[1], srcs[1], order[1], qb[0], kb[1], vb[1], aggb[0], AGB);
    // output linear + skip: l=0 -> new h bf16 into hb; l=1 -> fp32 d_out only
    if (l == 0) {
      mfgemm<1, false, true, false, false><<<2 * GB, blk, 0, stream>>>(
          aggb[0], aggb[1], NN, GB,
          woT, HID * HID, bo, HID,
          hb[0], nullptr, nullptr, hb[1], nullptr, nullptr,
          nullptr, nullptr, hb[0], hb[1], skipP, 0);
    } else {
      mfgemm<1, false, true, false, false><<<2 * GB, blk, 0, stream>>>(
          aggb[0], aggb[1], NN, GB,
          woT + (size_t)2 * HID * HID, HID * HID, bo + 2 * HID, HID,
          nullptr, nullptr, nullptr, nullptr, nullptr, nullptr,
          out, out + (size_t)NN * HID, hb[0], hb[1], skipP + 2, 1);
    }
  }
}

// Round 15
// 528.121 us; speedup vs baseline: 1.5686x; 1.5048x over previous
//
#include <hip/hip_runtime.h>
#include <stdint.h>
#include <stdio.h>

#define NN 100000
#define NE 500000
#define HID 128
#define NH 4
#define HD 32
#define LL 2
#define SCANB 1024
#define NB ((NN + SCANB - 1) / SCANB)

typedef unsigned short u16;
typedef unsigned char u8;
typedef unsigned int u32;
typedef __attribute__((ext_vector_type(8))) short bfrag;   // 8 bf16 = 4 VGPR
typedef __attribute__((ext_vector_type(4))) float f32x4;
typedef __attribute__((ext_vector_type(2))) float f32x2;

__device__ __forceinline__ float b2f(u32 lo16) {
  union { u32 u; float f; } c; c.u = lo16; return c.f;
}
__device__ __forceinline__ u16 f2b(float f) {
  union { float f; u32 u; } c; c.f = f;
  u32 u = c.u;
  u32 r = (u + 0x7FFFu + ((u >> 16) & 1u)) >> 16;
  return (u16)r;
}
__device__ __forceinline__ float geluf(float x) {
  return 0.5f * x * (1.0f + erff(x * 0.70710678118654752f));
}
__device__ __forceinline__ void up8(uint4 a, float* f) {
  f[0] = b2f(a.x << 16); f[1] = b2f(a.x & 0xFFFF0000u);
  f[2] = b2f(a.y << 16); f[3] = b2f(a.y & 0xFFFF0000u);
  f[4] = b2f(a.z << 16); f[5] = b2f(a.z & 0xFFFF0000u);
  f[6] = b2f(a.w << 16); f[7] = b2f(a.w & 0xFFFF0000u);
}

// ---------------- CSR build (both relations in one launch, blockIdx.y = r) ----
__global__ __launch_bounds__(256) void csr_count(const int* __restrict__ e0,
                                                 const int* __restrict__ e1,
                                                 int* __restrict__ deg) {
  int r = blockIdx.y;
  const int* edges = r ? e1 : e0;
  int e = blockIdx.x * 256 + threadIdx.x;
  if (e < NE) atomicAdd(&deg[(size_t)r * NN + edges[NE + e]], 1);
}

__global__ __launch_bounds__(SCANB) void scan1(const int* __restrict__ deg,
                                               int* __restrict__ rp,
                                               int* __restrict__ bsum) {
  __shared__ int ls[SCANB];
  int r = blockIdx.y;
  int t = threadIdx.x;
  int g = blockIdx.x * SCANB + t;
  int v = (g < NN) ? deg[(size_t)r * NN + g] : 0;
  ls[t] = v;
  __syncthreads();
#pragma unroll
  for (int off = 1; off < SCANB; off <<= 1) {
    int u = (t >= off) ? ls[t - off] : 0;
    __syncthreads();
    ls[t] += u;
    __syncthreads();
  }
  if (g < NN) rp[(size_t)r * (NN + 1) + g] = ls[t] - v;
  if (t == SCANB - 1) bsum[r * NB + blockIdx.x] = ls[t];
}

__global__ __launch_bounds__(128) void scan2(const int* __restrict__ bsum,
                                             int* __restrict__ boff) {
  __shared__ int ls[128];
  int r = blockIdx.y;
  int t = threadIdx.x;
  int v = (t < NB) ? bsum[r * NB + t] : 0;
  ls[t] = v;
  __syncthreads();
#pragma unroll
  for (int off = 1; off < 128; off <<= 1) {
    int u = (t >= off) ? ls[t - off] : 0;
    __syncthreads();
    ls[t] += u;
    __syncthreads();
  }
  if (t < NB) boff[r * NB + t] = ls[t] - v;
}

__global__ __launch_bounds__(SCANB) void scan3(int* __restrict__ rp,
                                               int* __restrict__ cursor,
                                               const int* __restrict__ boff) {
  int r = blockIdx.y;
  int g = blockIdx.x * SCANB + threadIdx.x;
  if (g < NN) {
    int v = rp[(size_t)r * (NN + 1) + g] + boff[r * NB + blockIdx.x];
    rp[(size_t)r * (NN + 1) + g] = v;
    cursor[(size_t)r * NN + g] = v;
  }
  if (g == 0) rp[(size_t)r * (NN + 1) + NN] = NE;
}

__global__ __launch_bounds__(256) void csr_fill(const int* __restrict__ e0,
                                                const int* __restrict__ e1,
                                                int* __restrict__ cursor,
                                                int* __restrict__ s0,
                                                int* __restrict__ s1) {
  int r = blockIdx.y;
  const int* edges = r ? e1 : e0;
  int* srcs = r ? s1 : s0;
  int e = blockIdx.x * 256 + threadIdx.x;
  if (e < NE) {
    int pos = atomicAdd(&cursor[(size_t)r * NN + edges[NE + e]], 1);
    srcs[pos] = edges[e];
  }
}

// ---------------- degree sort (two-level counting sort, keys 0..63) ----------------
__global__ __launch_bounds__(256) void hist_deg(const int* __restrict__ rp,
                                                int* __restrict__ hist) {
  __shared__ int lh[64];
  int r = blockIdx.y;
  if (threadIdx.x < 64) lh[threadIdx.x] = 0;
  __syncthreads();
  int d = blockIdx.x * 256 + threadIdx.x;
  if (d < NN) {
    const int* rowptr = rp + (size_t)r * (NN + 1);
    int dg = rowptr[d + 1] - rowptr[d];
    atomicAdd(&lh[dg < 63 ? dg : 63], 1);
  }
  __syncthreads();
  if (threadIdx.x < 64 && lh[threadIdx.x])
    atomicAdd(&hist[r * 64 + threadIdx.x], lh[threadIdx.x]);
}

__global__ __launch_bounds__(64) void scan_hist(const int* __restrict__ hist,
                                                int* __restrict__ hcur) {
  __shared__ int ls[64];
  int r = blockIdx.y;
  int t = threadIdx.x;
  int v = hist[r * 64 + t];
  ls[t] = v;
  __syncthreads();
#pragma unroll
  for (int off = 1; off < 64; off <<= 1) {
    int u = (t >= off) ? ls[t - off] : 0;
    __syncthreads();
    ls[t] += u;
    __syncthreads();
  }
  hcur[r * 64 + t] = ls[t] - v;
}

__global__ __launch_bounds__(256) void scatter_deg(const int* __restrict__ rp,
                                                   int* __restrict__ hcur,
                                                   int* __restrict__ o0,
                                                   int* __restrict__ o1) {
  __shared__ int lh[64];
  __shared__ int lbase[64];
  int r = blockIdx.y;
  int* order = r ? o1 : o0;
  if (threadIdx.x < 64) lh[threadIdx.x] = 0;
  __syncthreads();
  int d = blockIdx.x * 256 + threadIdx.x;
  int dg = 0, rank = 0;
  if (d < NN) {
    const int* rowptr = rp + (size_t)r * (NN + 1);
    dg = rowptr[d + 1] - rowptr[d];
    if (dg > 63) dg = 63;
    rank = atomicAdd(&lh[dg], 1);
  }
  __syncthreads();
  if (threadIdx.x < 64)
    lbase[threadIdx.x] = lh[threadIdx.x] ? atomicAdd(&hcur[r * 64 + threadIdx.x], lh[threadIdx.x]) : 0;
  __syncthreads();
  if (d < NN) order[lbase[dg] + rank] = d;
}

// ---------------- weight prep ----------------
__global__ __launch_bounds__(256) void prep_wT(const float* __restrict__ src, size_t srcStride,
                                               u16* __restrict__ dst, size_t dstStride,
                                               const float* __restrict__ bsrc, int bsStride,
                                               float* __restrict__ bdst, int bdStride,
                                               const float* __restrict__ p_rel_q) {
  int m = blockIdx.y;
  const float* S = src + (size_t)m * srcStride;
  u16* D = dst + (size_t)m * dstStride;
  int idx = blockIdx.x * 256 + threadIdx.x;
  int k = idx >> 7, n = idx & 127;
  float v = S[idx];
  if (p_rel_q != nullptr) {
    int l = m >> 1, t = m & 1;
    v *= p_rel_q[((l << 1) | (1 - t)) * NH + (n >> 5)] * 0.17677669529663687f;
  }
  D[(size_t)n * HID + k] = f2b(v);
  if (bsrc != nullptr && blockIdx.x == 0 && threadIdx.x < HID) {
    int col = threadIdx.x;
    float bvv = bsrc[(size_t)m * bsStride + col];
    if (p_rel_q != nullptr) {
      int l = m >> 1, t = m & 1;
      bvv *= p_rel_q[((l << 1) | (1 - t)) * NH + (col >> 5)] * 0.17677669529663687f;
    }
    bdst[(size_t)m * bdStride + col] = bvv;
  }
}

__global__ __launch_bounds__(256) void combine_all(
    const float* __restrict__ Wk, const float* __restrict__ bk,
    const float* __restrict__ Wv, const float* __restrict__ bv,
    const float* __restrict__ a_rel, const float* __restrict__ m_rel,
    u16* __restrict__ wqkvT, float* __restrict__ bqkv) {
  int l = blockIdx.z;
  int t = blockIdx.y >> 1, which = blockIdx.y & 1;
  const float* W  = (which == 0 ? Wk : Wv) + (size_t)(l * 2 + t) * HID * HID;
  const float* b  = (which == 0 ? bk : bv) + (size_t)(l * 2 + t) * HID;
  const float* Ar = (which == 0 ? a_rel : m_rel) + (size_t)(l * 2 + t) * NH * HD * HD;
  u16* Wd = wqkvT + ((size_t)(l * 2 + t) * 3 + 1 + which) * HID * HID;
  float* bd = bqkv + ((size_t)(l * 2 + t) * 3 + 1 + which) * HID;
  int idx = blockIdx.x * 256 + threadIdx.x;
  int i = idx >> 7, col = idx & 127;
  int h = col >> 5, e = col & 31;
  {
    const float* ap = Ar + h * HD * HD + e;
    const float* wp = W + (size_t)i * HID + h * HD;
    float s = 0.f;
#pragma unroll
    for (int d = 0; d < HD; ++d) s += wp[d] * ap[d * HD];
    Wd[(size_t)col * HID + i] = f2b(s);
  }
  if (blockIdx.x == 0 && threadIdx.x < HID) {
    int col2 = threadIdx.x, h2 = col2 >> 5, e2 = col2 & 31;
    const float* ap = Ar + h2 * HD * HD + e2;
    const float* bp = b + h2 * HD;
    float s = 0.f;
#pragma unroll
    for (int d = 0; d < HD; ++d) s += bp[d] * ap[d * HD];
    bd[col2] = s;
  }
}

// ---------------- qkv GEMM: 256 thr, 64KB double-buffered LDS, 3 barriers ----------
// t = blockIdx.x >= gb; one 128-row chunk per block. stage(m+1) issued BEFORE
// compute(m) (T3 2-phase minimum); buffers alternate; 2 blocks/CU.
__global__ __launch_bounds__(256) void qkv_gemm(
    const u16* __restrict__ h0, const u16* __restrict__ h1,
    const u16* __restrict__ WT,      // [t][3][n][k] bf16 (layer slice)
    const float* __restrict__ bias,  // [t][3][128]  (layer slice)
    u16* __restrict__ q0, u16* __restrict__ q1,
    u8* __restrict__ k0, u8* __restrict__ k1,
    u8* __restrict__ v0, u8* __restrict__ v1, int gb) {
  __shared__ __align__(16) u16 sW[2][HID * HID];   // 2 x 32 KB
  const int t = blockIdx.x >= gb;
  const int bx = t ? blockIdx.x - gb : blockIdx.x;
  const u16* A = t ? h1 : h0;
  const u16* Wg = WT + (size_t)t * 3 * HID * HID;
  const float* bs = bias + (size_t)t * 3 * HID;
  u16* Oq = t ? q1 : q0;
  u8* Ok = t ? k1 : k0;
  u8* Ov = t ? v1 : v0;

  const int lane = threadIdx.x & 63;
  const int wid = threadIdx.x >> 6;
  const int l16 = lane & 15, g = lane >> 4;
  const int rbase = bx * 128 + wid * 32;

  auto stageW = [&](int m, int buf) {
    const u16* Wm = Wg + (size_t)m * HID * HID;
#pragma unroll
    for (int j = 0; j < 8; ++j) {
      int ins = wid * 8 + j;
      int o16 = ins * 64 + lane;
      int row = o16 >> 4, ch = o16 & 15;
      const u16* src = Wm + (size_t)row * HID + ((ch ^ (row & 7)) << 3);
      u16* dst = &sW[buf][0] + (size_t)ins * 512;
      __builtin_amdgcn_global_load_lds(
          (const __attribute__((address_space(1))) unsigned int*)src,
          (__attribute__((address_space(3))) unsigned int*)dst, 16, 0, 0);
    }
  };

  // A fragments (in flight with first stage)
  bfrag af[2][4];
  int rowA[2];
#pragma unroll
  for (int rt = 0; rt < 2; ++rt) {
    int row = rbase + rt * 16 + l16;
    rowA[rt] = row;
    int rl = row < NN ? row : NN - 1;
    const bfrag* ap = (const bfrag*)(A + (size_t)rl * HID);
#pragma unroll
    for (int ks = 0; ks < 4; ++ks) af[rt][ks] = ap[ks * 4 + g];
  }

  stageW(0, 0);
  __syncthreads();

#pragma unroll
  for (int m = 0; m < 3; ++m) {
    if (m + 1 < 3) stageW(m + 1, (m + 1) & 1);   // issue BEFORE compute(m)
    f32x4 acc[2][8];
#pragma unroll
    for (int rt = 0; rt < 2; ++rt)
#pragma unroll
      for (int ct = 0; ct < 8; ++ct) acc[rt][ct] = (f32x4){0.f, 0.f, 0.f, 0.f};
#pragma unroll
    for (int ct = 0; ct < 8; ++ct) {
      int row = ct * 16 + l16;
      bfrag wf[4];
#pragma unroll
      for (int ks = 0; ks < 4; ++ks)
        wf[ks] = *(const bfrag*)&sW[m & 1][(size_t)row * HID +
                                           (((ks * 4 + g) ^ (row & 7)) << 3)];
#pragma unroll
      for (int ks = 0; ks < 4; ++ks)
#pragma unroll
        for (int rt = 0; rt < 2; ++rt)
          acc[rt][ct] = __builtin_amdgcn_mfma_f32_16x16x32_bf16(wf[ks], af[rt][ks],
                                                                acc[rt][ct], 0, 0, 0);
    }
#pragma unroll
    for (int rt = 0; rt < 2; ++rt) {
      int row = rowA[rt];
      if (row >= NN) continue;
#pragma unroll
      for (int ct = 0; ct < 8; ++ct) {
        int nc = ct * 16 + g * 4;
        const float4 bb = *(const float4*)(bs + m * HID + nc);
        float o0 = acc[rt][ct][0] + bb.x;
        float o1 = acc[rt][ct][1] + bb.y;
        float o2 = acc[rt][ct][2] + bb.z;
        float o3 = acc[rt][ct][3] + bb.w;
        if (m == 0) {
          u32 lo = (u32)f2b(o0) | ((u32)f2b(o1) << 16);
          u32 hi = (u32)f2b(o2) | ((u32)f2b(o3) << 16);
          *(uint2*)(Oq + (size_t)row * HID + nc) = make_uint2(lo, hi);
        } else {
          u8* O8 = (m == 1) ? Ok : Ov;
          u32 pk = __builtin_amdgcn_cvt_pk_fp8_f32(o0, o1, 0u, false);
          pk = __builtin_amdgcn_cvt_pk_fp8_f32(o2, o3, pk, true);
          *(u32*)(O8 + (size_t)row * HID + nc) = pk;
        }
      }
    }
    if (m + 1 < 3) __syncthreads();   // stage(m+1) complete; loads mostly drained
  }
}

// ---------------- generic MFMA GEMM (NMAT=1; input/out layers) ----------------
template <int NMAT, bool RELU, bool SKIP, bool FP8KV, bool AF32>
__global__ __launch_bounds__(256) void mfgemm(
    const void* __restrict__ A0, const void* __restrict__ A1, int M, int gb,
    const u16* __restrict__ WT, size_t wtStride,
    const float* __restrict__ bias, size_t biasStride,
    u16* __restrict__ O00, u16* __restrict__ O01, u16* __restrict__ O02,
    u16* __restrict__ O10, u16* __restrict__ O11, u16* __restrict__ O12,
    float* __restrict__ Of0, float* __restrict__ Of1,
    const u16* __restrict__ hp0, const u16* __restrict__ hp1,
    const float* __restrict__ skipP, int resflag) {
  __shared__ __align__(16) u16 sW[HID * HID];
  const int t = blockIdx.x >= gb;
  const int bx = t ? blockIdx.x - gb : blockIdx.x;
  const void* A = t ? A1 : A0;
  const u16* Wg = WT + (size_t)t * wtStride;
  const float* bs = bias + (size_t)t * biasStride;
  u16* Os[3];
  Os[0] = t ? O10 : O00; Os[1] = t ? O11 : O01; Os[2] = t ? O12 : O02;
  float* Of = t ? Of1 : Of0;
  const u16* hprev = t ? hp1 : hp0;

  const int lane = threadIdx.x & 63;
  const int wid = threadIdx.x >> 6;
  const int l16 = lane & 15, g = lane >> 4;
  const int rbase = bx * 128 + wid * 32;

  float beta = 0.f;
  if (SKIP) beta = 1.f / (1.f + __expf(-skipP[t]));

  auto stageW = [&](int m) {
    const u16* Wm = Wg + (size_t)m * HID * HID;
#pragma unroll
    for (int j = 0; j < 8; ++j) {
      int ins = wid * 8 + j;
      int o16 = ins * 64 + lane;
      int row = o16 >> 4, ch = o16 & 15;
      const u16* src = Wm + (size_t)row * HID + ((ch ^ (row & 7)) << 3);
      u16* dst = sW + (size_t)ins * 512;
      __builtin_amdgcn_global_load_lds(
          (const __attribute__((address_space(1))) unsigned int*)src,
          (__attribute__((address_space(3))) unsigned int*)dst, 16, 0, 0);
    }
  };

  bfrag af[2][4];
  int rowA[2];
#pragma unroll
  for (int rt = 0; rt < 2; ++rt) {
    int row = rbase + rt * 16 + l16;
    rowA[rt] = row;
    int rl = row < M ? row : M - 1;
    if (AF32) {
      const float* apf = (const float*)A + (size_t)rl * HID;
#pragma unroll
      for (int ks = 0; ks < 4; ++ks) {
        float4 u0 = *(const float4*)(apf + (ks * 4 + g) * 8);
        float4 u1 = *(const float4*)(apf + (ks * 4 + g) * 8 + 4);
        union { u16 s[8]; bfrag b; } pk;
        pk.s[0] = f2b(u0.x); pk.s[1] = f2b(u0.y); pk.s[2] = f2b(u0.z); pk.s[3] = f2b(u0.w);
        pk.s[4] = f2b(u1.x); pk.s[5] = f2b(u1.y); pk.s[6] = f2b(u1.z); pk.s[7] = f2b(u1.w);
        af[rt][ks] = pk.b;
      }
    } else {
      const bfrag* ap = (const bfrag*)A + (size_t)rl * (HID / 8);
#pragma unroll
      for (int ks = 0; ks < 4; ++ks) af[rt][ks] = ap[ks * 4 + g];
    }
  }

  stageW(0);
  __syncthreads();

#pragma unroll
  for (int m = 0; m < NMAT; ++m) {
    f32x4 acc[2][8];
#pragma unroll
    for (int rt = 0; rt < 2; ++rt)
#pragma unroll
      for (int ct = 0; ct < 8; ++ct) acc[rt][ct] = (f32x4){0.f, 0.f, 0.f, 0.f};
#pragma unroll
    for (int ct = 0; ct < 8; ++ct) {
      int row = ct * 16 + l16;
      bfrag wf[4];
#pragma unroll
      for (int ks = 0; ks < 4; ++ks)
        wf[ks] = *(const bfrag*)&sW[(size_t)row * HID + (((ks * 4 + g) ^ (row & 7)) << 3)];
#pragma unroll
      for (int ks = 0; ks < 4; ++ks)
#pragma unroll
        for (int rt = 0; rt < 2; ++rt)
          acc[rt][ct] = __builtin_amdgcn_mfma_f32_16x16x32_bf16(wf[ks], af[rt][ks],
                                                                acc[rt][ct], 0, 0, 0);
    }
    if (m + 1 < NMAT) {
      __syncthreads();
      stageW(m + 1);
    }
    u16* Ob = Os[m];
#pragma unroll
    for (int rt = 0; rt < 2; ++rt) {
      int row = rowA[rt];
      if (row >= M) continue;
#pragma unroll
      for (int ct = 0; ct < 8; ++ct) {
        int nc = ct * 16 + g * 4;
        const float4 bb = *(const float4*)(bs + m * HID + nc);
        float o0 = acc[rt][ct][0] + bb.x;
        float o1 = acc[rt][ct][1] + bb.y;
        float o2 = acc[rt][ct][2] + bb.z;
        float o3 = acc[rt][ct][3] + bb.w;
        if (RELU) {
          o0 = fmaxf(o0, 0.f); o1 = fmaxf(o1, 0.f);
          o2 = fmaxf(o2, 0.f); o3 = fmaxf(o3, 0.f);
        }
        if (SKIP) {
          uint2 hh2 = *(const uint2*)(hprev + (size_t)row * HID + nc);
          float h0 = b2f(hh2.x << 16), h1 = b2f(hh2.x & 0xFFFF0000u);
          float h2 = b2f(hh2.y << 16), h3 = b2f(hh2.y & 0xFFFF0000u);
          o0 = beta * o0 + (1.f - beta) * h0;
          o1 = beta * o1 + (1.f - beta) * h1;
          o2 = beta * o2 + (1.f - beta) * h2;
          o3 = beta * o3 + (1.f - beta) * h3;
          if (resflag) { o0 += h0; o1 += h1; o2 += h2; o3 += h3; }
        }
        if (FP8KV && m >= 1) {
          u32 pk = __builtin_amdgcn_cvt_pk_fp8_f32(o0, o1, 0u, false);
          pk = __builtin_amdgcn_cvt_pk_fp8_f32(o2, o3, pk, true);
          *(u32*)((u8*)Ob + (size_t)row * HID + nc) = pk;
        } else {
          if (Ob != nullptr) {
            u32 lo = (u32)f2b(o0) | ((u32)f2b(o1) << 16);
            u32 hi = (u32)f2b(o2) | ((u32)f2b(o3) << 16);
            *(uint2*)(Ob + (size_t)row * HID + nc) = make_uint2(lo, hi);
          }
          if (NMAT == 1 && Of != nullptr) {
            *(float4*)(Of + (size_t)row * HID + nc) = make_float4(o0, o1, o2, o3);
          }
        }
      }
    }
    if (m + 1 < NMAT) __syncthreads();
  }
}

// Fused per-(dst,head) attention gather, both relations in one launch.
__global__ __launch_bounds__(256) void agg_csr(
    const int* __restrict__ rp0, const int* __restrict__ ss0, const int* __restrict__ od0,
    const u16* __restrict__ q0, const u8* __restrict__ k0,
    const u8* __restrict__ v0, u16* __restrict__ o0,
    const int* __restrict__ rp1, const int* __restrict__ ss1, const int* __restrict__ od1,
    const u16* __restrict__ q1, const u8* __restrict__ k1,
    const u8* __restrict__ v1, u16* __restrict__ o1, int agb) {
  const int r = blockIdx.x >= agb;
  const int bx = r ? blockIdx.x - agb : blockIdx.x;
  int i = bx * 256 + threadIdx.x;
  if (i >= NN * NH) return;
  const int* rowptr = r ? rp1 : rp0;
  const int* srcs = r ? ss1 : ss0;
  const int* order = r ? od1 : od0;
  const u16* qT = r ? q1 : q0;
  const u8* kT = r ? k1 : k0;
  const u8* vT = r ? v1 : v0;
  u16* aggb = r ? o1 : o0;

  int dst = order[i >> 2], h = i & 3;
  float qv[HD];
  {
    const uint4* qp = (const uint4*)(qT + (size_t)dst * HID + h * HD);
#pragma unroll
    for (int j = 0; j < 4; ++j) up8(qp[j], qv + j * 8);
  }
  float acc[HD];
#pragma unroll
  for (int j = 0; j < HD; ++j) acc[j] = 0.f;
  float z = 0.f;
  int b = rowptr[dst], e2 = rowptr[dst + 1];
  for (int idx = b; idx < e2; ++idx) {
    int src = srcs[idx];
    const uint4* kp = (const uint4*)(kT + (size_t)src * HID + h * HD);
    const uint4* vp = (const uint4*)(vT + (size_t)src * HID + h * HD);
    uint4 ka0 = kp[0], ka1 = kp[1];
    uint4 va0 = vp[0], va1 = vp[1];
    u32 kw[8] = {ka0.x, ka0.y, ka0.z, ka0.w, ka1.x, ka1.y, ka1.z, ka1.w};
    u32 vw[8] = {va0.x, va0.y, va0.z, va0.w, va1.x, va1.y, va1.z, va1.w};
    float s = 0.f;
#pragma unroll
    for (int j = 0; j < 8; ++j) {
      f32x2 p0 = __builtin_amdgcn_cvt_pk_f32_fp8(kw[j], false);
      f32x2 p1 = __builtin_amdgcn_cvt_pk_f32_fp8(kw[j], true);
      s += qv[4 * j] * p0.x + qv[4 * j + 1] * p0.y + qv[4 * j + 2] * p1.x + qv[4 * j + 3] * p1.y;
    }
    s = fminf(s, 60.f);
    float ev = __expf(s);
    z += ev;
#pragma unroll
    for (int j = 0; j < 8; ++j) {
      f32x2 p0 = __builtin_amdgcn_cvt_pk_f32_fp8(vw[j], false);
      f32x2 p1 = __builtin_amdgcn_cvt_pk_f32_fp8(vw[j], true);
      acc[4 * j] += ev * p0.x; acc[4 * j + 1] += ev * p0.y;
      acc[4 * j + 2] += ev * p1.x; acc[4 * j + 3] += ev * p1.y;
    }
  }
  float inv = 1.f / (z + 1e-16f);
  u16* ap = aggb + (size_t)dst * HID + h * HD;
  u32 w[16];
#pragma unroll
  for (int j = 0; j < 16; ++j) {
    float a0 = geluf(acc[2 * j] * inv);
    float a1 = geluf(acc[2 * j + 1] * inv);
    w[j] = (u32)f2b(a0) | ((u32)f2b(a1) << 16);
  }
#pragma unroll
  for (int j = 0; j < 4; ++j)
    *(uint4*)(ap + j * 8) = make_uint4(w[4 * j], w[4 * j + 1], w[4 * j + 2], w[4 * j + 3]);
}

extern "C" void kernel_launch(void* const* d_in, const int* in_sizes, int n_in,
                              void* d_out, int out_size, void* d_ws, size_t ws_size,
                              hipStream_t stream) {
  const float* x_user = (const float*)d_in[0];
  const float* x_item = (const float*)d_in[1];
  const float* W_in = (const float*)d_in[2];
  const float* b_in = (const float*)d_in[3];
  const float* Wk = (const float*)d_in[4];
  const float* bk = (const float*)d_in[5];
  const float* Wq = (const float*)d_in[6];
  const float* bq = (const float*)d_in[7];
  const float* Wv = (const float*)d_in[8];
  const float* bv = (const float*)d_in[9];
  const float* a_rel = (const float*)d_in[10];
  const float* m_rel = (const float*)d_in[11];
  const float* p_rel = (const float*)d_in[12];
  const float* Wo = (const float*)d_in[13];
  const float* bo = (const float*)d_in[14];
  const float* skipP = (const float*)d_in[15];
  const int* edge_ui = (const int*)d_in[16];
  const int* edge_iu = (const int*)d_in[17];
  float* out = (float*)d_out;

  char* p = (char*)d_ws;
  auto take = [&](size_t bytes) {
    void* r = (void*)p;
    p += (bytes + 255) & ~(size_t)255;
    return r;
  };
  size_t nodeB = (size_t)NN * HID * sizeof(u16);
  size_t node8 = (size_t)NN * HID;
  u16* hb[2] = {(u16*)take(nodeB), (u16*)take(nodeB)};         // bf16 h (in-place updated)
  u16* qb[2] = {(u16*)take(nodeB), (u16*)take(nodeB)};         // bf16 q
  u8* kb[2] = {(u8*)take(node8), (u8*)take(node8)};            // fp8 k
  u8* vb[2] = {(u8*)take(node8), (u8*)take(node8)};            // fp8 v
  u16* aggb[2] = {(u16*)take(nodeB), (u16*)take(nodeB)};       // gelu'd agg bf16
  int* deg2   = (int*)take((size_t)2 * NN * 4);
  int* cur2   = (int*)take((size_t)2 * NN * 4);
  int* bsum2  = (int*)take((size_t)2 * NB * 4);
  int* boff2  = (int*)take((size_t)2 * NB * 4);
  int* hist2  = (int*)take((size_t)2 * 64 * 4);
  int* hcur2  = (int*)take((size_t)2 * 64 * 4);
  int* rp2    = (int*)take((size_t)2 * (NN + 1) * 4);
  int* srcs[2]  = {(int*)take((size_t)NE * 4), (int*)take((size_t)NE * 4)};
  int* order[2] = {(int*)take((size_t)NN * 4), (int*)take((size_t)NN * 4)};
  u16* winT  = (u16*)take((size_t)2 * HID * HID * 2);
  u16* woT   = (u16*)take((size_t)4 * HID * HID * 2);
  u16* wqkvT = (u16*)take((size_t)2 * 2 * 3 * HID * HID * 2);  // [l][t][q,k,v]
  float* bqkv = (float*)take((size_t)2 * 2 * 3 * HID * 4);
  size_t used = (size_t)(p - (char*)d_ws);
  if (used > ws_size) {
    fprintf(stderr, "HGT kernel: workspace too small: need %zu, have %zu\n", used, ws_size);
    return;
  }

  const int GB = (NN + 127) / 128;
  const int EB = (NE + 255) / 256;
  const int DB = (NN + 255) / 256;
  dim3 blk(256);

  // ---- CSR build + degree sort (merged across relations) ----
  hipMemsetAsync(deg2, 0, (size_t)2 * NN * 4, stream);
  csr_count<<<dim3(EB, 2), blk, 0, stream>>>(edge_ui, edge_iu, deg2);
  scan1<<<dim3(NB, 2), SCANB, 0, stream>>>(deg2, rp2, bsum2);
  scan2<<<dim3(1, 2), 128, 0, stream>>>(bsum2, boff2);
  scan3<<<dim3(NB, 2), SCANB, 0, stream>>>(rp2, cur2, boff2);
  csr_fill<<<dim3(EB, 2), blk, 0, stream>>>(edge_ui, edge_iu, cur2, srcs[0], srcs[1]);
  hipMemsetAsync(hist2, 0, 2 * 64 * 4, stream);
  hist_deg<<<dim3(DB, 2), blk, 0, stream>>>(rp2, hist2);
  scan_hist<<<dim3(1, 2), 64, 0, stream>>>(hist2, hcur2);
  scatter_deg<<<dim3(DB, 2), blk, 0, stream>>>(rp2, hcur2, order[0], order[1]);
  int* rowptr[2] = {rp2, rp2 + (NN + 1)};

  // ---- weight prep (all upfront, wide grids) ----
  prep_wT<<<dim3(64, 2), blk, 0, stream>>>(W_in, HID * HID, winT, HID * HID,
                                           nullptr, 0, nullptr, 0, nullptr);
  prep_wT<<<dim3(64, 4), blk, 0, stream>>>(Wo, HID * HID, woT, HID * HID,
                                           nullptr, 0, nullptr, 0, nullptr);
  prep_wT<<<dim3(64, 4), blk, 0, stream>>>(Wq, HID * HID, wqkvT, 3 * HID * HID,
                                           bq, HID, bqkv, 3 * HID, p_rel);
  combine_all<<<dim3(64, 4, 2), blk, 0, stream>>>(Wk, bk, Wv, bv, a_rel, m_rel,
                                                  wqkvT, bqkv);

  // ---- input linear + relu (x fp32 read directly; h written bf16 only) ----
  mfgemm<1, true, false, false, true><<<2 * GB, blk, 0, stream>>>(
      x_user, x_item, NN, GB, winT, HID * HID, b_in, HID,
      hb[0], nullptr, nullptr, hb[1], nullptr, nullptr,
      nullptr, nullptr, nullptr, nullptr, nullptr, 0);

  const int AGB = (NN * NH + 255) / 256;
  for (int l = 0; l < LL; ++l) {
    // q/k/v projections: 64KB dbuf LDS, stage-before-compute, 3 barriers
    qkv_gemm<<<2 * GB, blk, 0, stream>>>(
        hb[0], hb[1],
        wqkvT + (size_t)l * 2 * 3 * HID * HID,
        bqkv + (size_t)l * 2 * 3 * HID,
        qb[0], qb[1], kb[0], kb[1], vb[0], vb[1], GB);
    // attention gather, both relations (r: st=r, dt=1-r)
    agg_csr<<<2 * AGB, blk, 0, stream>>>(
        rowptr[0], srcs[0], order[0], qb[1], kb[0], vb[0], aggb[1],
        rowptr[1], srcs[1], order[1], qb[0], kb[1], vb[1], aggb[0], AGB);
    // output linear + skip: l=0 -> new h bf16 into hb; l=1 -> fp32 d_out only
    if (l == 0) {
      mfgemm<1, false, true, false, false><<<2 * GB, blk, 0, stream>>>(
          aggb[0], aggb[1], NN, GB,
          woT, HID * HID, bo, HID,
          hb[0], nullptr, nullptr, hb[1], nullptr, nullptr,
          nullptr, nullptr, hb[0], hb[1], skipP, 0);
    } else {
      mfgemm<1, false, true, false, false><<<2 * GB, blk, 0, stream>>>(
          aggb[0], aggb[1], NN, GB,
          woT + (size_t)2 * HID * HID, HID * HID, bo + 2 * HID, HID,
          nullptr, nullptr, nullptr, nullptr, nullptr, nullptr,
          out, out + (size_t)NN * HID, hb[0], hb[1], skipP + 2, 1);
    }
  }
}

// Round 16
// 509.378 us; speedup vs baseline: 1.6263x; 1.0368x over previous
//
#include <hip/hip_runtime.h>
#include <stdint.h>
#include <stdio.h>

#define NN 100000
#define NE 500000
#define HID 128
#define NH 4
#define HD 32
#define LL 2
#define SCANB 1024
#define NB ((NN + SCANB - 1) / SCANB)

typedef unsigned short u16;
typedef unsigned char u8;
typedef unsigned int u32;
typedef __attribute__((ext_vector_type(8))) short bfrag;   // 8 bf16 = 4 VGPR
typedef __attribute__((ext_vector_type(4))) float f32x4;
typedef __attribute__((ext_vector_type(2))) float f32x2;

__device__ __forceinline__ float b2f(u32 lo16) {
  union { u32 u; float f; } c; c.u = lo16; return c.f;
}
__device__ __forceinline__ u16 f2b(float f) {
  union { float f; u32 u; } c; c.f = f;
  u32 u = c.u;
  u32 r = (u + 0x7FFFu + ((u >> 16) & 1u)) >> 16;
  return (u16)r;
}
__device__ __forceinline__ float geluf(float x) {
  return 0.5f * x * (1.0f + erff(x * 0.70710678118654752f));
}
__device__ __forceinline__ void up8(uint4 a, float* f) {
  f[0] = b2f(a.x << 16); f[1] = b2f(a.x & 0xFFFF0000u);
  f[2] = b2f(a.y << 16); f[3] = b2f(a.y & 0xFFFF0000u);
  f[4] = b2f(a.z << 16); f[5] = b2f(a.z & 0xFFFF0000u);
  f[6] = b2f(a.w << 16); f[7] = b2f(a.w & 0xFFFF0000u);
}
__device__ __forceinline__ float dot32(uint4 a, uint4 b, const float* qv) {
  u32 w[8] = {a.x, a.y, a.z, a.w, b.x, b.y, b.z, b.w};
  float s = 0.f;
#pragma unroll
  for (int j = 0; j < 8; ++j) {
    f32x2 p0 = __builtin_amdgcn_cvt_pk_f32_fp8(w[j], false);
    f32x2 p1 = __builtin_amdgcn_cvt_pk_f32_fp8(w[j], true);
    s += qv[4 * j] * p0.x + qv[4 * j + 1] * p0.y + qv[4 * j + 2] * p1.x + qv[4 * j + 3] * p1.y;
  }
  return s;
}
__device__ __forceinline__ void acc32(uint4 a, uint4 b, float ev, float* acc) {
  u32 w[8] = {a.x, a.y, a.z, a.w, b.x, b.y, b.z, b.w};
#pragma unroll
  for (int j = 0; j < 8; ++j) {
    f32x2 p0 = __builtin_amdgcn_cvt_pk_f32_fp8(w[j], false);
    f32x2 p1 = __builtin_amdgcn_cvt_pk_f32_fp8(w[j], true);
    acc[4 * j] += ev * p0.x; acc[4 * j + 1] += ev * p0.y;
    acc[4 * j + 2] += ev * p1.x; acc[4 * j + 3] += ev * p1.y;
  }
}

// ---------------- CSR build (both relations in one launch, blockIdx.y = r) ----
// also zeroes hist (block 0) so no separate memset is needed.
__global__ __launch_bounds__(256) void csr_count(const int* __restrict__ e0,
                                                 const int* __restrict__ e1,
                                                 int* __restrict__ deg,
                                                 int* __restrict__ hist) {
  if (blockIdx.x == 0 && blockIdx.y == 0 && threadIdx.x < 128) hist[threadIdx.x] = 0;
  int r = blockIdx.y;
  const int* edges = r ? e1 : e0;
  int e = blockIdx.x * 256 + threadIdx.x;
  if (e < NE) atomicAdd(&deg[(size_t)r * NN + edges[NE + e]], 1);
}

// block-local exclusive scan of deg + 64-bin degree histogram (merged hist_deg)
__global__ __launch_bounds__(SCANB) void scan1(const int* __restrict__ deg,
                                               int* __restrict__ rp,
                                               int* __restrict__ bsum,
                                               int* __restrict__ hist) {
  __shared__ int ls[SCANB];
  __shared__ int lh[64];
  int r = blockIdx.y;
  int t = threadIdx.x;
  int g = blockIdx.x * SCANB + t;
  int v = (g < NN) ? deg[(size_t)r * NN + g] : 0;
  ls[t] = v;
  if (t < 64) lh[t] = 0;
  __syncthreads();
  if (g < NN) atomicAdd(&lh[v < 63 ? v : 63], 1);
#pragma unroll
  for (int off = 1; off < SCANB; off <<= 1) {
    int u = (t >= off) ? ls[t - off] : 0;
    __syncthreads();
    ls[t] += u;
    __syncthreads();
  }
  if (g < NN) rp[(size_t)r * (NN + 1) + g] = ls[t] - v;
  if (t == SCANB - 1) bsum[r * NB + blockIdx.x] = ls[t];
  if (t < 64 && lh[t]) atomicAdd(&hist[r * 64 + t], lh[t]);
}

// block-sum scan + histogram scan (merged scan_hist)
__global__ __launch_bounds__(128) void scan2(const int* __restrict__ bsum,
                                             int* __restrict__ boff,
                                             const int* __restrict__ hist,
                                             int* __restrict__ hcur) {
  __shared__ int ls[128];
  int r = blockIdx.y;
  int t = threadIdx.x;
  int v = (t < NB) ? bsum[r * NB + t] : 0;
  ls[t] = v;
  __syncthreads();
#pragma unroll
  for (int off = 1; off < 128; off <<= 1) {
    int u = (t >= off) ? ls[t - off] : 0;
    __syncthreads();
    ls[t] += u;
    __syncthreads();
  }
  if (t < NB) boff[r * NB + t] = ls[t] - v;
  __syncthreads();
  int hv = (t < 64) ? hist[r * 64 + t] : 0;
  ls[t] = hv;
  __syncthreads();
#pragma unroll
  for (int off = 1; off < 64; off <<= 1) {
    int u = (t >= off) ? ls[t - off] : 0;
    __syncthreads();
    ls[t] += u;
    __syncthreads();
  }
  if (t < 64) hcur[r * 64 + t] = ls[t] - hv;
}

// finalize rowptr/cursor + degree-sorted order scatter (merged scatter_deg)
__global__ __launch_bounds__(SCANB) void scan3(int* __restrict__ rp,
                                               int* __restrict__ cursor,
                                               const int* __restrict__ boff,
                                               const int* __restrict__ deg,
                                               int* __restrict__ hcur,
                                               int* __restrict__ o0,
                                               int* __restrict__ o1) {
  __shared__ int lh[64];
  __shared__ int lbase[64];
  int r = blockIdx.y;
  int* order = r ? o1 : o0;
  int t = threadIdx.x;
  int g = blockIdx.x * SCANB + t;
  if (t < 64) lh[t] = 0;
  int dg = 0;
  if (g < NN) {
    int v = rp[(size_t)r * (NN + 1) + g] + boff[r * NB + blockIdx.x];
    rp[(size_t)r * (NN + 1) + g] = v;
    cursor[(size_t)r * NN + g] = v;
    dg = deg[(size_t)r * NN + g];
    if (dg > 63) dg = 63;
  }
  if (g == 0) rp[(size_t)r * (NN + 1) + NN] = NE;
  __syncthreads();
  int rank = 0;
  if (g < NN) rank = atomicAdd(&lh[dg], 1);
  __syncthreads();
  if (t < 64)
    lbase[t] = lh[t] ? atomicAdd(&hcur[r * 64 + t], lh[t]) : 0;
  __syncthreads();
  if (g < NN) order[lbase[dg] + rank] = g;
}

__global__ __launch_bounds__(256) void csr_fill(const int* __restrict__ e0,
                                                const int* __restrict__ e1,
                                                int* __restrict__ cursor,
                                                int* __restrict__ s0,
                                                int* __restrict__ s1) {
  int r = blockIdx.y;
  const int* edges = r ? e1 : e0;
  int* srcs = r ? s1 : s0;
  int e = blockIdx.x * 256 + threadIdx.x;
  if (e < NE) {
    int pos = atomicAdd(&cursor[(size_t)r * NN + edges[NE + e]], 1);
    srcs[pos] = edges[e];
  }
}

// ---------------- all weight prep in ONE launch: grid (64, 18) ----------------
// y 0-1: W_in->winT; y 2-5: Wo->woT; y 6-9: Wq->wqkvT slot0 (+p_rel/sqrtD, bias);
// y 10-17: (Wk.a_rel)^T / (Wv.m_rel)^T -> slots 1/2 (+bias).
__global__ __launch_bounds__(256) void prep_all(
    const float* __restrict__ W_in,
    const float* __restrict__ Wo,
    const float* __restrict__ Wq, const float* __restrict__ bq,
    const float* __restrict__ Wk, const float* __restrict__ bk,
    const float* __restrict__ Wv, const float* __restrict__ bv,
    const float* __restrict__ a_rel, const float* __restrict__ m_rel,
    const float* __restrict__ p_rel,
    u16* __restrict__ winT, u16* __restrict__ woT,
    u16* __restrict__ wqkvT, float* __restrict__ bqkv) {
  const float scale = 0.17677669529663687f;  // 1/sqrt(32)
  int y = blockIdx.y;
  int idx = blockIdx.x * 256 + threadIdx.x;
  if (y < 10) {
    const float* src; u16* dst;
    const float* bsrc = nullptr; float* bdst = nullptr;
    bool useP = false; int m = 0;
    if (y < 2) {
      m = y; src = W_in + (size_t)m * HID * HID; dst = winT + (size_t)m * HID * HID;
    } else if (y < 6) {
      m = y - 2; src = Wo + (size_t)m * HID * HID; dst = woT + (size_t)m * HID * HID;
    } else {
      m = y - 6; src = Wq + (size_t)m * HID * HID;
      dst = wqkvT + (size_t)m * 3 * HID * HID;
      useP = true; bsrc = bq + (size_t)m * HID; bdst = bqkv + (size_t)m * 3 * HID;
    }
    int k = idx >> 7, n = idx & 127;
    float v = src[idx];
    if (useP) {
      int l = m >> 1, t = m & 1;
      v *= p_rel[((l << 1) | (1 - t)) * NH + (n >> 5)] * scale;
    }
    dst[(size_t)n * HID + k] = f2b(v);
    if (bdst != nullptr && blockIdx.x == 0 && threadIdx.x < HID) {
      int col = threadIdx.x;
      int l = m >> 1, t = m & 1;
      bdst[col] = bsrc[col] * p_rel[((l << 1) | (1 - t)) * NH + (col >> 5)] * scale;
    }
  } else {
    int c = y - 10;           // 0..7
    int l = c >> 2, t = (c >> 1) & 1, which = c & 1;
    const float* W  = (which == 0 ? Wk : Wv) + (size_t)(l * 2 + t) * HID * HID;
    const float* b  = (which == 0 ? bk : bv) + (size_t)(l * 2 + t) * HID;
    const float* Ar = (which == 0 ? a_rel : m_rel) + (size_t)(l * 2 + t) * NH * HD * HD;
    u16* Wd = wqkvT + ((size_t)(l * 2 + t) * 3 + 1 + which) * HID * HID;
    float* bd = bqkv + ((size_t)(l * 2 + t) * 3 + 1 + which) * HID;
    int i = idx >> 7, col = idx & 127;
    int h = col >> 5, e = col & 31;
    {
      const float* ap = Ar + h * HD * HD + e;
      const float* wp = W + (size_t)i * HID + h * HD;
      float s = 0.f;
#pragma unroll
      for (int d = 0; d < HD; ++d) s += wp[d] * ap[d * HD];
      Wd[(size_t)col * HID + i] = f2b(s);
    }
    if (blockIdx.x == 0 && threadIdx.x < HID) {
      int col2 = threadIdx.x, h2 = col2 >> 5, e2 = col2 & 31;
      const float* ap = Ar + h2 * HD * HD + e2;
      const float* bp = b + h2 * HD;
      float s = 0.f;
#pragma unroll
      for (int d = 0; d < HD; ++d) s += bp[d] * ap[d * HD];
      bd[col2] = s;
    }
  }
}

// ---------------- qkv GEMM: 256 thr, 64KB double-buffered LDS, 3 barriers ----------
__global__ __launch_bounds__(256) void qkv_gemm(
    const u16* __restrict__ h0, const u16* __restrict__ h1,
    const u16* __restrict__ WT,      // [t][3][n][k] bf16 (layer slice)
    const float* __restrict__ bias,  // [t][3][128]  (layer slice)
    u16* __restrict__ q0, u16* __restrict__ q1,
    u8* __restrict__ k0, u8* __restrict__ k1,
    u8* __restrict__ v0, u8* __restrict__ v1, int gb) {
  __shared__ __align__(16) u16 sW[2][HID * HID];   // 2 x 32 KB
  const int t = blockIdx.x >= gb;
  const int bx = t ? blockIdx.x - gb : blockIdx.x;
  const u16* A = t ? h1 : h0;
  const u16* Wg = WT + (size_t)t * 3 * HID * HID;
  const float* bs = bias + (size_t)t * 3 * HID;
  u16* Oq = t ? q1 : q0;
  u8* Ok = t ? k1 : k0;
  u8* Ov = t ? v1 : v0;

  const int lane = threadIdx.x & 63;
  const int wid = threadIdx.x >> 6;
  const int l16 = lane & 15, g = lane >> 4;
  const int rbase = bx * 128 + wid * 32;

  auto stageW = [&](int m, int buf) {
    const u16* Wm = Wg + (size_t)m * HID * HID;
#pragma unroll
    for (int j = 0; j < 8; ++j) {
      int ins = wid * 8 + j;
      int o16 = ins * 64 + lane;
      int row = o16 >> 4, ch = o16 & 15;
      const u16* src = Wm + (size_t)row * HID + ((ch ^ (row & 7)) << 3);
      u16* dst = &sW[buf][0] + (size_t)ins * 512;
      __builtin_amdgcn_global_load_lds(
          (const __attribute__((address_space(1))) unsigned int*)src,
          (__attribute__((address_space(3))) unsigned int*)dst, 16, 0, 0);
    }
  };

  bfrag af[2][4];
  int rowA[2];
#pragma unroll
  for (int rt = 0; rt < 2; ++rt) {
    int row = rbase + rt * 16 + l16;
    rowA[rt] = row;
    int rl = row < NN ? row : NN - 1;
    const bfrag* ap = (const bfrag*)(A + (size_t)rl * HID);
#pragma unroll
    for (int ks = 0; ks < 4; ++ks) af[rt][ks] = ap[ks * 4 + g];
  }

  stageW(0, 0);
  __syncthreads();

#pragma unroll
  for (int m = 0; m < 3; ++m) {
    if (m + 1 < 3) stageW(m + 1, (m + 1) & 1);   // issue BEFORE compute(m)
    f32x4 acc[2][8];
#pragma unroll
    for (int rt = 0; rt < 2; ++rt)
#pragma unroll
      for (int ct = 0; ct < 8; ++ct) acc[rt][ct] = (f32x4){0.f, 0.f, 0.f, 0.f};
#pragma unroll
    for (int ct = 0; ct < 8; ++ct) {
      int row = ct * 16 + l16;
      bfrag wf[4];
#pragma unroll
      for (int ks = 0; ks < 4; ++ks)
        wf[ks] = *(const bfrag*)&sW[m & 1][(size_t)row * HID +
                                           (((ks * 4 + g) ^ (row & 7)) << 3)];
#pragma unroll
      for (int ks = 0; ks < 4; ++ks)
#pragma unroll
        for (int rt = 0; rt < 2; ++rt)
          acc[rt][ct] = __builtin_amdgcn_mfma_f32_16x16x32_bf16(wf[ks], af[rt][ks],
                                                                acc[rt][ct], 0, 0, 0);
    }
#pragma unroll
    for (int rt = 0; rt < 2; ++rt) {
      int row = rowA[rt];
      if (row >= NN) continue;
#pragma unroll
      for (int ct = 0; ct < 8; ++ct) {
        int nc = ct * 16 + g * 4;
        const float4 bb = *(const float4*)(bs + m * HID + nc);
        float o0 = acc[rt][ct][0] + bb.x;
        float o1 = acc[rt][ct][1] + bb.y;
        float o2 = acc[rt][ct][2] + bb.z;
        float o3 = acc[rt][ct][3] + bb.w;
        if (m == 0) {
          u32 lo = (u32)f2b(o0) | ((u32)f2b(o1) << 16);
          u32 hi = (u32)f2b(o2) | ((u32)f2b(o3) << 16);
          *(uint2*)(Oq + (size_t)row * HID + nc) = make_uint2(lo, hi);
        } else {
          u8* O8 = (m == 1) ? Ok : Ov;
          u32 pk = __builtin_amdgcn_cvt_pk_fp8_f32(o0, o1, 0u, false);
          pk = __builtin_amdgcn_cvt_pk_fp8_f32(o2, o3, pk, true);
          *(u32*)(O8 + (size_t)row * HID + nc) = pk;
        }
      }
    }
    if (m + 1 < 3) __syncthreads();
  }
}

// ---------------- generic MFMA GEMM (NMAT=1; input/out layers) ----------------
template <int NMAT, bool RELU, bool SKIP, bool FP8KV, bool AF32>
__global__ __launch_bounds__(256) void mfgemm(
    const void* __restrict__ A0, const void* __restrict__ A1, int M, int gb,
    const u16* __restrict__ WT, size_t wtStride,
    const float* __restrict__ bias, size_t biasStride,
    u16* __restrict__ O00, u16* __restrict__ O01, u16* __restrict__ O02,
    u16* __restrict__ O10, u16* __restrict__ O11, u16* __restrict__ O12,
    float* __restrict__ Of0, float* __restrict__ Of1,
    const u16* __restrict__ hp0, const u16* __restrict__ hp1,
    const float* __restrict__ skipP, int resflag) {
  __shared__ __align__(16) u16 sW[HID * HID];
  const int t = blockIdx.x >= gb;
  const int bx = t ? blockIdx.x - gb : blockIdx.x;
  const void* A = t ? A1 : A0;
  const u16* Wg = WT + (size_t)t * wtStride;
  const float* bs = bias + (size_t)t * biasStride;
  u16* Os[3];
  Os[0] = t ? O10 : O00; Os[1] = t ? O11 : O01; Os[2] = t ? O12 : O02;
  float* Of = t ? Of1 : Of0;
  const u16* hprev = t ? hp1 : hp0;

  const int lane = threadIdx.x & 63;
  const int wid = threadIdx.x >> 6;
  const int l16 = lane & 15, g = lane >> 4;
  const int rbase = bx * 128 + wid * 32;

  float beta = 0.f;
  if (SKIP) beta = 1.f / (1.f + __expf(-skipP[t]));

  auto stageW = [&](int m) {
    const u16* Wm = Wg + (size_t)m * HID * HID;
#pragma unroll
    for (int j = 0; j < 8; ++j) {
      int ins = wid * 8 + j;
      int o16 = ins * 64 + lane;
      int row = o16 >> 4, ch = o16 & 15;
      const u16* src = Wm + (size_t)row * HID + ((ch ^ (row & 7)) << 3);
      u16* dst = sW + (size_t)ins * 512;
      __builtin_amdgcn_global_load_lds(
          (const __attribute__((address_space(1))) unsigned int*)src,
          (__attribute__((address_space(3))) unsigned int*)dst, 16, 0, 0);
    }
  };

  bfrag af[2][4];
  int rowA[2];
#pragma unroll
  for (int rt = 0; rt < 2; ++rt) {
    int row = rbase + rt * 16 + l16;
    rowA[rt] = row;
    int rl = row < M ? row : M - 1;
    if (AF32) {
      const float* apf = (const float*)A + (size_t)rl * HID;
#pragma unroll
      for (int ks = 0; ks < 4; ++ks) {
        float4 u0 = *(const float4*)(apf + (ks * 4 + g) * 8);
        float4 u1 = *(const float4*)(apf + (ks * 4 + g) * 8 + 4);
        union { u16 s[8]; bfrag b; } pk;
        pk.s[0] = f2b(u0.x); pk.s[1] = f2b(u0.y); pk.s[2] = f2b(u0.z); pk.s[3] = f2b(u0.w);
        pk.s[4] = f2b(u1.x); pk.s[5] = f2b(u1.y); pk.s[6] = f2b(u1.z); pk.s[7] = f2b(u1.w);
        af[rt][ks] = pk.b;
      }
    } else {
      const bfrag* ap = (const bfrag*)A + (size_t)rl * (HID / 8);
#pragma unroll
      for (int ks = 0; ks < 4; ++ks) af[rt][ks] = ap[ks * 4 + g];
    }
  }

  stageW(0);
  __syncthreads();

#pragma unroll
  for (int m = 0; m < NMAT; ++m) {
    f32x4 acc[2][8];
#pragma unroll
    for (int rt = 0; rt < 2; ++rt)
#pragma unroll
      for (int ct = 0; ct < 8; ++ct) acc[rt][ct] = (f32x4){0.f, 0.f, 0.f, 0.f};
#pragma unroll
    for (int ct = 0; ct < 8; ++ct) {
      int row = ct * 16 + l16;
      bfrag wf[4];
#pragma unroll
      for (int ks = 0; ks < 4; ++ks)
        wf[ks] = *(const bfrag*)&sW[(size_t)row * HID + (((ks * 4 + g) ^ (row & 7)) << 3)];
#pragma unroll
      for (int ks = 0; ks < 4; ++ks)
#pragma unroll
        for (int rt = 0; rt < 2; ++rt)
          acc[rt][ct] = __builtin_amdgcn_mfma_f32_16x16x32_bf16(wf[ks], af[rt][ks],
                                                                acc[rt][ct], 0, 0, 0);
    }
    if (m + 1 < NMAT) {
      __syncthreads();
      stageW(m + 1);
    }
    u16* Ob = Os[m];
#pragma unroll
    for (int rt = 0; rt < 2; ++rt) {
      int row = rowA[rt];
      if (row >= M) continue;
#pragma unroll
      for (int ct = 0; ct < 8; ++ct) {
        int nc = ct * 16 + g * 4;
        const float4 bb = *(const float4*)(bs + m * HID + nc);
        float o0 = acc[rt][ct][0] + bb.x;
        float o1 = acc[rt][ct][1] + bb.y;
        float o2 = acc[rt][ct][2] + bb.z;
        float o3 = acc[rt][ct][3] + bb.w;
        if (RELU) {
          o0 = fmaxf(o0, 0.f); o1 = fmaxf(o1, 0.f);
          o2 = fmaxf(o2, 0.f); o3 = fmaxf(o3, 0.f);
        }
        if (SKIP) {
          uint2 hh2 = *(const uint2*)(hprev + (size_t)row * HID + nc);
          float h0 = b2f(hh2.x << 16), h1 = b2f(hh2.x & 0xFFFF0000u);
          float h2 = b2f(hh2.y << 16), h3 = b2f(hh2.y & 0xFFFF0000u);
          o0 = beta * o0 + (1.f - beta) * h0;
          o1 = beta * o1 + (1.f - beta) * h1;
          o2 = beta * o2 + (1.f - beta) * h2;
          o3 = beta * o3 + (1.f - beta) * h3;
          if (resflag) { o0 += h0; o1 += h1; o2 += h2; o3 += h3; }
        }
        if (FP8KV && m >= 1) {
          u32 pk = __builtin_amdgcn_cvt_pk_fp8_f32(o0, o1, 0u, false);
          pk = __builtin_amdgcn_cvt_pk_fp8_f32(o2, o3, pk, true);
          *(u32*)((u8*)Ob + (size_t)row * HID + nc) = pk;
        } else {
          if (Ob != nullptr) {
            u32 lo = (u32)f2b(o0) | ((u32)f2b(o1) << 16);
            u32 hi = (u32)f2b(o2) | ((u32)f2b(o3) << 16);
            *(uint2*)(Ob + (size_t)row * HID + nc) = make_uint2(lo, hi);
          }
          if (NMAT == 1 && Of != nullptr) {
            *(float4*)(Of + (size_t)row * HID + nc) = make_float4(o0, o1, o2, o3);
          }
        }
      }
    }
    if (m + 1 < NMAT) __syncthreads();
  }
}

// Fused per-(dst,head) attention gather, both relations in one launch.
// fp8 k/v; degree-sorted order; edge loop unrolled x2 for memory-level parallelism.
__global__ __launch_bounds__(256) void agg_csr(
    const int* __restrict__ rp0, const int* __restrict__ ss0, const int* __restrict__ od0,
    const u16* __restrict__ q0, const u8* __restrict__ k0,
    const u8* __restrict__ v0, u16* __restrict__ o0,
    const int* __restrict__ rp1, const int* __restrict__ ss1, const int* __restrict__ od1,
    const u16* __restrict__ q1, const u8* __restrict__ k1,
    const u8* __restrict__ v1, u16* __restrict__ o1, int agb) {
  const int r = blockIdx.x >= agb;
  const int bx = r ? blockIdx.x - agb : blockIdx.x;
  int i = bx * 256 + threadIdx.x;
  if (i >= NN * NH) return;
  const int* rowptr = r ? rp1 : rp0;
  const int* srcs = r ? ss1 : ss0;
  const int* order = r ? od1 : od0;
  const u16* qT = r ? q1 : q0;
  const u8* kT = r ? k1 : k0;
  const u8* vT = r ? v1 : v0;
  u16* aggb = r ? o1 : o0;

  int dst = order[i >> 2], h = i & 3;
  float qv[HD];
  {
    const uint4* qp = (const uint4*)(qT + (size_t)dst * HID + h * HD);
#pragma unroll
    for (int j = 0; j < 4; ++j) up8(qp[j], qv + j * 8);
  }
  float acc[HD];
#pragma unroll
  for (int j = 0; j < HD; ++j) acc[j] = 0.f;
  float z = 0.f;
  int b = rowptr[dst], e2 = rowptr[dst + 1];
  int idx = b;
  for (; idx + 2 <= e2; idx += 2) {
    int s0 = srcs[idx], s1 = srcs[idx + 1];
    const uint4* kp0 = (const uint4*)(kT + (size_t)s0 * HID + h * HD);
    const uint4* vp0 = (const uint4*)(vT + (size_t)s0 * HID + h * HD);
    const uint4* kp1 = (const uint4*)(kT + (size_t)s1 * HID + h * HD);
    const uint4* vp1 = (const uint4*)(vT + (size_t)s1 * HID + h * HD);
    uint4 kA = kp0[0], kB = kp0[1];
    uint4 kC = kp1[0], kD = kp1[1];
    uint4 vA = vp0[0], vB = vp0[1];
    uint4 vC = vp1[0], vD = vp1[1];
    float d0 = dot32(kA, kB, qv);
    float d1 = dot32(kC, kD, qv);
    float ev0 = __expf(fminf(d0, 60.f));
    float ev1 = __expf(fminf(d1, 60.f));
    z += ev0 + ev1;
    acc32(vA, vB, ev0, acc);
    acc32(vC, vD, ev1, acc);
  }
  if (idx < e2) {
    int s0 = srcs[idx];
    const uint4* kp0 = (const uint4*)(kT + (size_t)s0 * HID + h * HD);
    const uint4* vp0 = (const uint4*)(vT + (size_t)s0 * HID + h * HD);
    uint4 kA = kp0[0], kB = kp0[1];
    uint4 vA = vp0[0], vB = vp0[1];
    float d0 = dot32(kA, kB, qv);
    float ev0 = __expf(fminf(d0, 60.f));
    z += ev0;
    acc32(vA, vB, ev0, acc);
  }
  float inv = 1.f / (z + 1e-16f);
  u16* ap = aggb + (size_t)dst * HID + h * HD;
  u32 w[16];
#pragma unroll
  for (int j = 0; j < 16; ++j) {
    float a0 = geluf(acc[2 * j] * inv);
    float a1 = geluf(acc[2 * j + 1] * inv);
    w[j] = (u32)f2b(a0) | ((u32)f2b(a1) << 16);
  }
#pragma unroll
  for (int j = 0; j < 4; ++j)
    *(uint4*)(ap + j * 8) = make_uint4(w[4 * j], w[4 * j + 1], w[4 * j + 2], w[4 * j + 3]);
}

extern "C" void kernel_launch(void* const* d_in, const int* in_sizes, int n_in,
                              void* d_out, int out_size, void* d_ws, size_t ws_size,
                              hipStream_t stream) {
  const float* x_user = (const float*)d_in[0];
  const float* x_item = (const float*)d_in[1];
  const float* W_in = (const float*)d_in[2];
  const float* b_in = (const float*)d_in[3];
  const float* Wk = (const float*)d_in[4];
  const float* bk = (const float*)d_in[5];
  const float* Wq = (const float*)d_in[6];
  const float* bq = (const float*)d_in[7];
  const float* Wv = (const float*)d_in[8];
  const float* bv = (const float*)d_in[9];
  const float* a_rel = (const float*)d_in[10];
  const float* m_rel = (const float*)d_in[11];
  const float* p_rel = (const float*)d_in[12];
  const float* Wo = (const float*)d_in[13];
  const float* bo = (const float*)d_in[14];
  const float* skipP = (const float*)d_in[15];
  const int* edge_ui = (const int*)d_in[16];
  const int* edge_iu = (const int*)d_in[17];
  float* out = (float*)d_out;

  char* p = (char*)d_ws;
  auto take = [&](size_t bytes) {
    void* r = (void*)p;
    p += (bytes + 255) & ~(size_t)255;
    return r;
  };
  size_t nodeB = (size_t)NN * HID * sizeof(u16);
  size_t node8 = (size_t)NN * HID;
  u16* hb[2] = {(u16*)take(nodeB), (u16*)take(nodeB)};         // bf16 h (in-place updated)
  u16* qb[2] = {(u16*)take(nodeB), (u16*)take(nodeB)};         // bf16 q
  u8* kb[2] = {(u8*)take(node8), (u8*)take(node8)};            // fp8 k
  u8* vb[2] = {(u8*)take(node8), (u8*)take(node8)};            // fp8 v
  u16* aggb[2] = {(u16*)take(nodeB), (u16*)take(nodeB)};       // gelu'd agg bf16
  int* deg2   = (int*)take((size_t)2 * NN * 4);
  int* cur2   = (int*)take((size_t)2 * NN * 4);
  int* bsum2  = (int*)take((size_t)2 * NB * 4);
  int* boff2  = (int*)take((size_t)2 * NB * 4);
  int* hist2  = (int*)take((size_t)2 * 64 * 4);
  int* hcur2  = (int*)take((size_t)2 * 64 * 4);
  int* rp2    = (int*)take((size_t)2 * (NN + 1) * 4);
  int* srcs[2]  = {(int*)take((size_t)NE * 4), (int*)take((size_t)NE * 4)};
  int* order[2] = {(int*)take((size_t)NN * 4), (int*)take((size_t)NN * 4)};
  u16* winT  = (u16*)take((size_t)2 * HID * HID * 2);
  u16* woT   = (u16*)take((size_t)4 * HID * HID * 2);
  u16* wqkvT = (u16*)take((size_t)2 * 2 * 3 * HID * HID * 2);  // [l][t][q,k,v]
  float* bqkv = (float*)take((size_t)2 * 2 * 3 * HID * 4);
  size_t used = (size_t)(p - (char*)d_ws);
  if (used > ws_size) {
    fprintf(stderr, "HGT kernel: workspace too small: need %zu, have %zu\n", used, ws_size);
    return;
  }

  const int GB = (NN + 127) / 128;
  const int EB = (NE + 255) / 256;
  dim3 blk(256);

  // ---- prologue: 7 dispatches ----
  hipMemsetAsync(deg2, 0, (size_t)2 * NN * 4, stream);
  prep_all<<<dim3(64, 18), blk, 0, stream>>>(W_in, Wo, Wq, bq, Wk, bk, Wv, bv,
                                             a_rel, m_rel, p_rel,
                                             winT, woT, wqkvT, bqkv);
  csr_count<<<dim3(EB, 2), blk, 0, stream>>>(edge_ui, edge_iu, deg2, hist2);
  scan1<<<dim3(NB, 2), SCANB, 0, stream>>>(deg2, rp2, bsum2, hist2);
  scan2<<<dim3(1, 2), 128, 0, stream>>>(bsum2, boff2, hist2, hcur2);
  scan3<<<dim3(NB, 2), SCANB, 0, stream>>>(rp2, cur2, boff2, deg2, hcur2,
                                           order[0], order[1]);
  csr_fill<<<dim3(EB, 2), blk, 0, stream>>>(edge_ui, edge_iu, cur2, srcs[0], srcs[1]);
  int* rowptr[2] = {rp2, rp2 + (NN + 1)};

  // ---- input linear + relu (x fp32 read directly; h written bf16 only) ----
  mfgemm<1, true, false, false, true><<<2 * GB, blk, 0, stream>>>(
      x_user, x_item, NN, GB, winT, HID * HID, b_in, HID,
      hb[0], nullptr, nullptr, hb[1], nullptr, nullptr,
      nullptr, nullptr, nullptr, nullptr, nullptr, 0);

  const int AGB = (NN * NH + 255) / 256;
  for (int l = 0; l < LL; ++l) {
    // q/k/v projections: 64KB dbuf LDS, stage-before-compute, 3 barriers
    qkv_gemm<<<2 * GB, blk, 0, stream>>>(
        hb[0], hb[1],
        wqkvT + (size_t)l * 2 * 3 * HID * HID,
        bqkv + (size_t)l * 2 * 3 * HID,
        qb[0], qb[1], kb[0], kb[1], vb[0], vb[1], GB);
    // attention gather, both relations (r: st=r, dt=1-r)
    agg_csr<<<2 * AGB, blk, 0, stream>>>(
        rowptr[0], srcs[0], order[0], qb[1], kb[0], vb[0], aggb[1],
        rowptr[1], srcs[1], order[1], qb[0], kb[1], vb[1], aggb[0], AGB);
    // output linear + skip: l=0 -> new h bf16 into hb; l=1 -> fp32 d_out only
    if (l == 0) {
      mfgemm<1, false, true, false, false><<<2 * GB, blk, 0, stream>>>(
          aggb[0], aggb[1], NN, GB,
          woT, HID * HID, bo, HID,
          hb[0], nullptr, nullptr, hb[1], nullptr, nullptr,
          nullptr, nullptr, hb[0], hb[1], skipP, 0);
    } else {
      mfgemm<1, false, true, false, false><<<2 * GB, blk, 0, stream>>>(
          aggb[0], aggb[1], NN, GB,
          woT + (size_t)2 * HID * HID, HID * HID, bo + 2 * HID, HID,
          nullptr, nullptr, nullptr, nullptr, nullptr, nullptr,
          out, out + (size_t)NN * HID, hb[0], hb[1], skipP + 2, 1);
    }
  }
}

// Round 17
// 492.662 us; speedup vs baseline: 1.6815x; 1.0339x over previous
//
#include <hip/hip_runtime.h>
#include <stdint.h>
#include <stdio.h>

#define NN 100000
#define NE 500000
#define HID 128
#define NH 4
#define HD 32
#define LL 2
#define SCANB 1024
#define NB ((NN + SCANB - 1) / SCANB)

typedef unsigned short u16;
typedef unsigned char u8;
typedef unsigned int u32;
typedef __attribute__((ext_vector_type(8))) short bfrag;   // 8 bf16 = 4 VGPR
typedef __attribute__((ext_vector_type(4))) float f32x4;
typedef __attribute__((ext_vector_type(2))) float f32x2;

__device__ __forceinline__ float b2f(u32 lo16) {
  union { u32 u; float f; } c; c.u = lo16; return c.f;
}
__device__ __forceinline__ u16 f2b(float f) {
  union { float f; u32 u; } c; c.f = f;
  u32 u = c.u;
  u32 r = (u + 0x7FFFu + ((u >> 16) & 1u)) >> 16;
  return (u16)r;
}
__device__ __forceinline__ float geluf(float x) {
  return 0.5f * x * (1.0f + erff(x * 0.70710678118654752f));
}
__device__ __forceinline__ void up8(uint4 a, float* f) {
  f[0] = b2f(a.x << 16); f[1] = b2f(a.x & 0xFFFF0000u);
  f[2] = b2f(a.y << 16); f[3] = b2f(a.y & 0xFFFF0000u);
  f[4] = b2f(a.z << 16); f[5] = b2f(a.z & 0xFFFF0000u);
  f[6] = b2f(a.w << 16); f[7] = b2f(a.w & 0xFFFF0000u);
}
__device__ __forceinline__ float dot32(uint4 a, uint4 b, const float* qv) {
  u32 w[8] = {a.x, a.y, a.z, a.w, b.x, b.y, b.z, b.w};
  float s = 0.f;
#pragma unroll
  for (int j = 0; j < 8; ++j) {
    f32x2 p0 = __builtin_amdgcn_cvt_pk_f32_fp8(w[j], false);
    f32x2 p1 = __builtin_amdgcn_cvt_pk_f32_fp8(w[j], true);
    s += qv[4 * j] * p0.x + qv[4 * j + 1] * p0.y + qv[4 * j + 2] * p1.x + qv[4 * j + 3] * p1.y;
  }
  return s;
}
__device__ __forceinline__ void acc32(uint4 a, uint4 b, float ev, float* acc) {
  u32 w[8] = {a.x, a.y, a.z, a.w, b.x, b.y, b.z, b.w};
#pragma unroll
  for (int j = 0; j < 8; ++j) {
    f32x2 p0 = __builtin_amdgcn_cvt_pk_f32_fp8(w[j], false);
    f32x2 p1 = __builtin_amdgcn_cvt_pk_f32_fp8(w[j], true);
    acc[4 * j] += ev * p0.x; acc[4 * j + 1] += ev * p0.y;
    acc[4 * j + 2] += ev * p1.x; acc[4 * j + 3] += ev * p1.y;
  }
}

// ---------------- CSR build (both relations in one launch, blockIdx.y = r) ----
__global__ __launch_bounds__(256) void csr_count(const int* __restrict__ e0,
                                                 const int* __restrict__ e1,
                                                 int* __restrict__ deg,
                                                 int* __restrict__ hist) {
  if (blockIdx.x == 0 && blockIdx.y == 0 && threadIdx.x < 128) hist[threadIdx.x] = 0;
  int r = blockIdx.y;
  const int* edges = r ? e1 : e0;
  int e = blockIdx.x * 256 + threadIdx.x;
  if (e < NE) atomicAdd(&deg[(size_t)r * NN + edges[NE + e]], 1);
}

__global__ __launch_bounds__(SCANB) void scan1(const int* __restrict__ deg,
                                               int* __restrict__ rp,
                                               int* __restrict__ bsum,
                                               int* __restrict__ hist) {
  __shared__ int ls[SCANB];
  __shared__ int lh[64];
  int r = blockIdx.y;
  int t = threadIdx.x;
  int g = blockIdx.x * SCANB + t;
  int v = (g < NN) ? deg[(size_t)r * NN + g] : 0;
  ls[t] = v;
  if (t < 64) lh[t] = 0;
  __syncthreads();
  if (g < NN) atomicAdd(&lh[v < 63 ? v : 63], 1);
#pragma unroll
  for (int off = 1; off < SCANB; off <<= 1) {
    int u = (t >= off) ? ls[t - off] : 0;
    __syncthreads();
    ls[t] += u;
    __syncthreads();
  }
  if (g < NN) rp[(size_t)r * (NN + 1) + g] = ls[t] - v;
  if (t == SCANB - 1) bsum[r * NB + blockIdx.x] = ls[t];
  if (t < 64 && lh[t]) atomicAdd(&hist[r * 64 + t], lh[t]);
}

__global__ __launch_bounds__(128) void scan2(const int* __restrict__ bsum,
                                             int* __restrict__ boff,
                                             const int* __restrict__ hist,
                                             int* __restrict__ hcur) {
  __shared__ int ls[128];
  int r = blockIdx.y;
  int t = threadIdx.x;
  int v = (t < NB) ? bsum[r * NB + t] : 0;
  ls[t] = v;
  __syncthreads();
#pragma unroll
  for (int off = 1; off < 128; off <<= 1) {
    int u = (t >= off) ? ls[t - off] : 0;
    __syncthreads();
    ls[t] += u;
    __syncthreads();
  }
  if (t < NB) boff[r * NB + t] = ls[t] - v;
  __syncthreads();
  int hv = (t < 64) ? hist[r * 64 + t] : 0;
  ls[t] = hv;
  __syncthreads();
#pragma unroll
  for (int off = 1; off < 64; off <<= 1) {
    int u = (t >= off) ? ls[t - off] : 0;
    __syncthreads();
    ls[t] += u;
    __syncthreads();
  }
  if (t < 64) hcur[r * 64 + t] = ls[t] - hv;
}

__global__ __launch_bounds__(SCANB) void scan3(int* __restrict__ rp,
                                               int* __restrict__ cursor,
                                               const int* __restrict__ boff,
                                               const int* __restrict__ deg,
                                               int* __restrict__ hcur,
                                               int* __restrict__ o0,
                                               int* __restrict__ o1) {
  __shared__ int lh[64];
  __shared__ int lbase[64];
  int r = blockIdx.y;
  int* order = r ? o1 : o0;
  int t = threadIdx.x;
  int g = blockIdx.x * SCANB + t;
  if (t < 64) lh[t] = 0;
  int dg = 0;
  if (g < NN) {
    int v = rp[(size_t)r * (NN + 1) + g] + boff[r * NB + blockIdx.x];
    rp[(size_t)r * (NN + 1) + g] = v;
    cursor[(size_t)r * NN + g] = v;
    dg = deg[(size_t)r * NN + g];
    if (dg > 63) dg = 63;
  }
  if (g == 0) rp[(size_t)r * (NN + 1) + NN] = NE;
  __syncthreads();
  int rank = 0;
  if (g < NN) rank = atomicAdd(&lh[dg], 1);
  __syncthreads();
  if (t < 64)
    lbase[t] = lh[t] ? atomicAdd(&hcur[r * 64 + t], lh[t]) : 0;
  __syncthreads();
  if (g < NN) order[lbase[dg] + rank] = g;
}

__global__ __launch_bounds__(256) void csr_fill(const int* __restrict__ e0,
                                                const int* __restrict__ e1,
                                                int* __restrict__ cursor,
                                                int* __restrict__ s0,
                                                int* __restrict__ s1) {
  int r = blockIdx.y;
  const int* edges = r ? e1 : e0;
  int* srcs = r ? s1 : s0;
  int e = blockIdx.x * 256 + threadIdx.x;
  if (e < NE) {
    int pos = atomicAdd(&cursor[(size_t)r * NN + edges[NE + e]], 1);
    srcs[pos] = edges[e];
  }
}

// ---------------- all weight prep in ONE launch: grid (64, 18) ----------------
__global__ __launch_bounds__(256) void prep_all(
    const float* __restrict__ W_in,
    const float* __restrict__ Wo,
    const float* __restrict__ Wq, const float* __restrict__ bq,
    const float* __restrict__ Wk, const float* __restrict__ bk,
    const float* __restrict__ Wv, const float* __restrict__ bv,
    const float* __restrict__ a_rel, const float* __restrict__ m_rel,
    const float* __restrict__ p_rel,
    u16* __restrict__ winT, u16* __restrict__ woT,
    u16* __restrict__ wqkvT, float* __restrict__ bqkv) {
  const float scale = 0.17677669529663687f;  // 1/sqrt(32)
  int y = blockIdx.y;
  int idx = blockIdx.x * 256 + threadIdx.x;
  if (y < 10) {
    const float* src; u16* dst;
    const float* bsrc = nullptr; float* bdst = nullptr;
    bool useP = false; int m = 0;
    if (y < 2) {
      m = y; src = W_in + (size_t)m * HID * HID; dst = winT + (size_t)m * HID * HID;
    } else if (y < 6) {
      m = y - 2; src = Wo + (size_t)m * HID * HID; dst = woT + (size_t)m * HID * HID;
    } else {
      m = y - 6; src = Wq + (size_t)m * HID * HID;
      dst = wqkvT + (size_t)m * 3 * HID * HID;
      useP = true; bsrc = bq + (size_t)m * HID; bdst = bqkv + (size_t)m * 3 * HID;
    }
    int k = idx >> 7, n = idx & 127;
    float v = src[idx];
    if (useP) {
      int l = m >> 1, t = m & 1;
      v *= p_rel[((l << 1) | (1 - t)) * NH + (n >> 5)] * scale;
    }
    dst[(size_t)n * HID + k] = f2b(v);
    if (bdst != nullptr && blockIdx.x == 0 && threadIdx.x < HID) {
      int col = threadIdx.x;
      int l = m >> 1, t = m & 1;
      bdst[col] = bsrc[col] * p_rel[((l << 1) | (1 - t)) * NH + (col >> 5)] * scale;
    }
  } else {
    int c = y - 10;           // 0..7
    int l = c >> 2, t = (c >> 1) & 1, which = c & 1;
    const float* W  = (which == 0 ? Wk : Wv) + (size_t)(l * 2 + t) * HID * HID;
    const float* b  = (which == 0 ? bk : bv) + (size_t)(l * 2 + t) * HID;
    const float* Ar = (which == 0 ? a_rel : m_rel) + (size_t)(l * 2 + t) * NH * HD * HD;
    u16* Wd = wqkvT + ((size_t)(l * 2 + t) * 3 + 1 + which) * HID * HID;
    float* bd = bqkv + ((size_t)(l * 2 + t) * 3 + 1 + which) * HID;
    int i = idx >> 7, col = idx & 127;
    int h = col >> 5, e = col & 31;
    {
      const float* ap = Ar + h * HD * HD + e;
      const float* wp = W + (size_t)i * HID + h * HD;
      float s = 0.f;
#pragma unroll
      for (int d = 0; d < HD; ++d) s += wp[d] * ap[d * HD];
      Wd[(size_t)col * HID + i] = f2b(s);
    }
    if (blockIdx.x == 0 && threadIdx.x < HID) {
      int col2 = threadIdx.x, h2 = col2 >> 5, e2 = col2 & 31;
      const float* ap = Ar + h2 * HD * HD + e2;
      const float* bp = b + h2 * HD;
      float s = 0.f;
#pragma unroll
      for (int d = 0; d < HD; ++d) s += bp[d] * ap[d * HD];
      bd[col2] = s;
    }
  }
}

// ---------------- qkv GEMM: 64KB dbuf LDS + LDS-transpose coalesced stores --------
// After compute(m), buf[m&1] is dead -> reuse as transpose tile. All global
// stores fully coalesced (16B/lane contiguous runs).
__global__ __launch_bounds__(256) void qkv_gemm(
    const u16* __restrict__ h0, const u16* __restrict__ h1,
    const u16* __restrict__ WT,      // [t][3][n][k] bf16 (layer slice)
    const float* __restrict__ bias,  // [t][3][128]  (layer slice)
    u16* __restrict__ q0, u16* __restrict__ q1,
    u8* __restrict__ k0, u8* __restrict__ k1,
    u8* __restrict__ v0, u8* __restrict__ v1, int gb) {
  __shared__ __align__(16) u16 sW[2][HID * HID];   // 2 x 32 KB
  const int t = blockIdx.x >= gb;
  const int bx = t ? blockIdx.x - gb : blockIdx.x;
  const u16* A = t ? h1 : h0;
  const u16* Wg = WT + (size_t)t * 3 * HID * HID;
  const float* bs = bias + (size_t)t * 3 * HID;
  u16* Oq = t ? q1 : q0;
  u8* Ok = t ? k1 : k0;
  u8* Ov = t ? v1 : v0;

  const int lane = threadIdx.x & 63;
  const int wid = threadIdx.x >> 6;
  const int l16 = lane & 15, g = lane >> 4;
  const int rbase = bx * 128 + wid * 32;

  auto stageW = [&](int m, int buf) {
    const u16* Wm = Wg + (size_t)m * HID * HID;
#pragma unroll
    for (int j = 0; j < 8; ++j) {
      int ins = wid * 8 + j;
      int o16 = ins * 64 + lane;
      int row = o16 >> 4, ch = o16 & 15;
      const u16* src = Wm + (size_t)row * HID + ((ch ^ (row & 7)) << 3);
      u16* dst = &sW[buf][0] + (size_t)ins * 512;
      __builtin_amdgcn_global_load_lds(
          (const __attribute__((address_space(1))) unsigned int*)src,
          (__attribute__((address_space(3))) unsigned int*)dst, 16, 0, 0);
    }
  };

  bfrag af[2][4];
#pragma unroll
  for (int rt = 0; rt < 2; ++rt) {
    int row = rbase + rt * 16 + l16;
    int rl = row < NN ? row : NN - 1;
    const bfrag* ap = (const bfrag*)(A + (size_t)rl * HID);
#pragma unroll
    for (int ks = 0; ks < 4; ++ks) af[rt][ks] = ap[ks * 4 + g];
  }

  stageW(0, 0);
  __syncthreads();

  const int rr = threadIdx.x >> 1, half = threadIdx.x & 1;
  const int grow = bx * 128 + rr;

#pragma unroll
  for (int m = 0; m < 3; ++m) {
    if (m + 1 < 3) stageW(m + 1, (m + 1) & 1);   // issue BEFORE compute(m)
    f32x4 acc[2][8];
#pragma unroll
    for (int rt = 0; rt < 2; ++rt)
#pragma unroll
      for (int ct = 0; ct < 8; ++ct) acc[rt][ct] = (f32x4){0.f, 0.f, 0.f, 0.f};
#pragma unroll
    for (int ct = 0; ct < 8; ++ct) {
      int row = ct * 16 + l16;
      bfrag wf[4];
#pragma unroll
      for (int ks = 0; ks < 4; ++ks)
        wf[ks] = *(const bfrag*)&sW[m & 1][(size_t)row * HID +
                                           (((ks * 4 + g) ^ (row & 7)) << 3)];
#pragma unroll
      for (int ks = 0; ks < 4; ++ks)
#pragma unroll
        for (int rt = 0; rt < 2; ++rt)
          acc[rt][ct] = __builtin_amdgcn_mfma_f32_16x16x32_bf16(wf[ks], af[rt][ks],
                                                                acc[rt][ct], 0, 0, 0);
    }
    __syncthreads();               // (a) all waves done reading W(m) in buf[m&1]
    u16* tile = &sW[m & 1][0];
    u8* t8 = (u8*)tile;
    // ---- write finalized outputs into the freed buffer, row-major, swizzled ----
#pragma unroll
    for (int rt = 0; rt < 2; ++rt) {
      int r = wid * 32 + rt * 16 + l16;
#pragma unroll
      for (int ct = 0; ct < 8; ++ct) {
        int nc = ct * 16 + g * 4;
        const float4 bb = *(const float4*)(bs + m * HID + nc);
        float o0 = acc[rt][ct][0] + bb.x;
        float o1 = acc[rt][ct][1] + bb.y;
        float o2 = acc[rt][ct][2] + bb.z;
        float o3 = acc[rt][ct][3] + bb.w;
        if (m == 0) {
          u32 lo = (u32)f2b(o0) | ((u32)f2b(o1) << 16);
          u32 hi = (u32)f2b(o2) | ((u32)f2b(o3) << 16);
          int sg = ((nc >> 3) ^ (r & 7));       // 16B group of u16 row
          *(uint2*)&tile[(size_t)r * HID + sg * 8 + (nc & 7)] = make_uint2(lo, hi);
        } else {
          u32 pk = __builtin_amdgcn_cvt_pk_fp8_f32(o0, o1, 0u, false);
          pk = __builtin_amdgcn_cvt_pk_fp8_f32(o2, o3, pk, true);
          int sg = ((nc >> 4) ^ (r & 7));       // 16B group of u8 row
          *(u32*)&t8[(size_t)r * HID + sg * 16 + (nc & 15)] = pk;
        }
      }
    }
    __syncthreads();               // (b) tile complete
    // ---- coalesced copy to global ----
    if (grow < NN) {
      if (m == 0) {
#pragma unroll
        for (int i = 0; i < 8; ++i) {
          int gg = half * 8 + i;
          uint4 d = *(const uint4*)&tile[(size_t)rr * HID + ((gg ^ (rr & 7)) * 8)];
          *(uint4*)(Oq + (size_t)grow * HID + gg * 8) = d;
        }
      } else {
        u8* O8 = (m == 1) ? Ok : Ov;
#pragma unroll
        for (int i = 0; i < 4; ++i) {
          int gg = half * 4 + i;
          uint4 d = *(const uint4*)&t8[(size_t)rr * HID + ((gg ^ (rr & 7)) * 16)];
          *(uint4*)(O8 + (size_t)grow * HID + gg * 16) = d;
        }
      }
    }
    if (m + 1 < 3) __syncthreads();   // (c) tile reads done; stage(m+1) arrived
  }
}

// ---------------- generic MFMA GEMM (NMAT=1; input/out layers) ----------------
// Ob path (bf16 output) uses LDS-transpose coalesced stores (reuses sW).
template <int NMAT, bool RELU, bool SKIP, bool FP8KV, bool AF32>
__global__ __launch_bounds__(256) void mfgemm(
    const void* __restrict__ A0, const void* __restrict__ A1, int M, int gb,
    const u16* __restrict__ WT, size_t wtStride,
    const float* __restrict__ bias, size_t biasStride,
    u16* __restrict__ O00, u16* __restrict__ O01, u16* __restrict__ O02,
    u16* __restrict__ O10, u16* __restrict__ O11, u16* __restrict__ O12,
    float* __restrict__ Of0, float* __restrict__ Of1,
    const u16* __restrict__ hp0, const u16* __restrict__ hp1,
    const float* __restrict__ skipP, int resflag) {
  __shared__ __align__(16) u16 sW[HID * HID];
  const int t = blockIdx.x >= gb;
  const int bx = t ? blockIdx.x - gb : blockIdx.x;
  const void* A = t ? A1 : A0;
  const u16* Wg = WT + (size_t)t * wtStride;
  const float* bs = bias + (size_t)t * biasStride;
  u16* Ob = t ? O10 : O00;
  float* Of = t ? Of1 : Of0;
  const u16* hprev = t ? hp1 : hp0;

  const int lane = threadIdx.x & 63;
  const int wid = threadIdx.x >> 6;
  const int l16 = lane & 15, g = lane >> 4;
  const int rbase = bx * 128 + wid * 32;

  float beta = 0.f;
  if (SKIP) beta = 1.f / (1.f + __expf(-skipP[t]));

  {
    const u16* Wm = Wg;
#pragma unroll
    for (int j = 0; j < 8; ++j) {
      int ins = wid * 8 + j;
      int o16 = ins * 64 + lane;
      int row = o16 >> 4, ch = o16 & 15;
      const u16* src = Wm + (size_t)row * HID + ((ch ^ (row & 7)) << 3);
      u16* dst = sW + (size_t)ins * 512;
      __builtin_amdgcn_global_load_lds(
          (const __attribute__((address_space(1))) unsigned int*)src,
          (__attribute__((address_space(3))) unsigned int*)dst, 16, 0, 0);
    }
  }

  bfrag af[2][4];
  int rowA[2];
#pragma unroll
  for (int rt = 0; rt < 2; ++rt) {
    int row = rbase + rt * 16 + l16;
    rowA[rt] = row;
    int rl = row < M ? row : M - 1;
    if (AF32) {
      const float* apf = (const float*)A + (size_t)rl * HID;
#pragma unroll
      for (int ks = 0; ks < 4; ++ks) {
        float4 u0 = *(const float4*)(apf + (ks * 4 + g) * 8);
        float4 u1 = *(const float4*)(apf + (ks * 4 + g) * 8 + 4);
        union { u16 s[8]; bfrag b; } pk;
        pk.s[0] = f2b(u0.x); pk.s[1] = f2b(u0.y); pk.s[2] = f2b(u0.z); pk.s[3] = f2b(u0.w);
        pk.s[4] = f2b(u1.x); pk.s[5] = f2b(u1.y); pk.s[6] = f2b(u1.z); pk.s[7] = f2b(u1.w);
        af[rt][ks] = pk.b;
      }
    } else {
      const bfrag* ap = (const bfrag*)A + (size_t)rl * (HID / 8);
#pragma unroll
      for (int ks = 0; ks < 4; ++ks) af[rt][ks] = ap[ks * 4 + g];
    }
  }

  __syncthreads();

  f32x4 acc[2][8];
#pragma unroll
  for (int rt = 0; rt < 2; ++rt)
#pragma unroll
    for (int ct = 0; ct < 8; ++ct) acc[rt][ct] = (f32x4){0.f, 0.f, 0.f, 0.f};
#pragma unroll
  for (int ct = 0; ct < 8; ++ct) {
    int row = ct * 16 + l16;
    bfrag wf[4];
#pragma unroll
    for (int ks = 0; ks < 4; ++ks)
      wf[ks] = *(const bfrag*)&sW[(size_t)row * HID + (((ks * 4 + g) ^ (row & 7)) << 3)];
#pragma unroll
    for (int ks = 0; ks < 4; ++ks)
#pragma unroll
      for (int rt = 0; rt < 2; ++rt)
        acc[rt][ct] = __builtin_amdgcn_mfma_f32_16x16x32_bf16(wf[ks], af[rt][ks],
                                                              acc[rt][ct], 0, 0, 0);
  }

  if (Ob != nullptr) {
    // ---- transpose path: finalized bf16 rows via LDS, coalesced stores ----
    __syncthreads();           // W reads complete; sW free
#pragma unroll
    for (int rt = 0; rt < 2; ++rt) {
      int r = wid * 32 + rt * 16 + l16;
      int row = rowA[rt];
      int rl = row < M ? row : M - 1;
#pragma unroll
      for (int ct = 0; ct < 8; ++ct) {
        int nc = ct * 16 + g * 4;
        const float4 bb = *(const float4*)(bs + nc);
        float o0 = acc[rt][ct][0] + bb.x;
        float o1 = acc[rt][ct][1] + bb.y;
        float o2 = acc[rt][ct][2] + bb.z;
        float o3 = acc[rt][ct][3] + bb.w;
        if (RELU) {
          o0 = fmaxf(o0, 0.f); o1 = fmaxf(o1, 0.f);
          o2 = fmaxf(o2, 0.f); o3 = fmaxf(o3, 0.f);
        }
        if (SKIP) {
          uint2 hh2 = *(const uint2*)(hprev + (size_t)rl * HID + nc);
          float h0 = b2f(hh2.x << 16), h1 = b2f(hh2.x & 0xFFFF0000u);
          float h2 = b2f(hh2.y << 16), h3 = b2f(hh2.y & 0xFFFF0000u);
          o0 = beta * o0 + (1.f - beta) * h0;
          o1 = beta * o1 + (1.f - beta) * h1;
          o2 = beta * o2 + (1.f - beta) * h2;
          o3 = beta * o3 + (1.f - beta) * h3;
          if (resflag) { o0 += h0; o1 += h1; o2 += h2; o3 += h3; }
        }
        u32 lo = (u32)f2b(o0) | ((u32)f2b(o1) << 16);
        u32 hi = (u32)f2b(o2) | ((u32)f2b(o3) << 16);
        int sg = ((nc >> 3) ^ (r & 7));
        *(uint2*)&sW[(size_t)r * HID + sg * 8 + (nc & 7)] = make_uint2(lo, hi);
      }
    }
    __syncthreads();
    int rr = threadIdx.x >> 1, half = threadIdx.x & 1;
    int grow = bx * 128 + rr;
    if (grow < M) {
#pragma unroll
      for (int i = 0; i < 8; ++i) {
        int gg = half * 8 + i;
        uint4 d = *(const uint4*)&sW[(size_t)rr * HID + ((gg ^ (rr & 7)) * 8)];
        *(uint4*)(Ob + (size_t)grow * HID + gg * 8) = d;
      }
    }
  } else {
    // ---- fp32 output path (final layer): direct float4 stores ----
#pragma unroll
    for (int rt = 0; rt < 2; ++rt) {
      int row = rowA[rt];
      if (row >= M) continue;
#pragma unroll
      for (int ct = 0; ct < 8; ++ct) {
        int nc = ct * 16 + g * 4;
        const float4 bb = *(const float4*)(bs + nc);
        float o0 = acc[rt][ct][0] + bb.x;
        float o1 = acc[rt][ct][1] + bb.y;
        float o2 = acc[rt][ct][2] + bb.z;
        float o3 = acc[rt][ct][3] + bb.w;
        if (RELU) {
          o0 = fmaxf(o0, 0.f); o1 = fmaxf(o1, 0.f);
          o2 = fmaxf(o2, 0.f); o3 = fmaxf(o3, 0.f);
        }
        if (SKIP) {
          uint2 hh2 = *(const uint2*)(hprev + (size_t)row * HID + nc);
          float h0 = b2f(hh2.x << 16), h1 = b2f(hh2.x & 0xFFFF0000u);
          float h2 = b2f(hh2.y << 16), h3 = b2f(hh2.y & 0xFFFF0000u);
          o0 = beta * o0 + (1.f - beta) * h0;
          o1 = beta * o1 + (1.f - beta) * h1;
          o2 = beta * o2 + (1.f - beta) * h2;
          o3 = beta * o3 + (1.f - beta) * h3;
          if (resflag) { o0 += h0; o1 += h1; o2 += h2; o3 += h3; }
        }
        *(float4*)(Of + (size_t)row * HID + nc) = make_float4(o0, o1, o2, o3);
      }
    }
  }
}

// Fused per-(dst,head) attention gather, both relations in one launch.
__global__ __launch_bounds__(256) void agg_csr(
    const int* __restrict__ rp0, const int* __restrict__ ss0, const int* __restrict__ od0,
    const u16* __restrict__ q0, const u8* __restrict__ k0,
    const u8* __restrict__ v0, u16* __restrict__ o0,
    const int* __restrict__ rp1, const int* __restrict__ ss1, const int* __restrict__ od1,
    const u16* __restrict__ q1, const u8* __restrict__ k1,
    const u8* __restrict__ v1, u16* __restrict__ o1, int agb) {
  const int r = blockIdx.x >= agb;
  const int bx = r ? blockIdx.x - agb : blockIdx.x;
  int i = bx * 256 + threadIdx.x;
  if (i >= NN * NH) return;
  const int* rowptr = r ? rp1 : rp0;
  const int* srcs = r ? ss1 : ss0;
  const int* order = r ? od1 : od0;
  const u16* qT = r ? q1 : q0;
  const u8* kT = r ? k1 : k0;
  const u8* vT = r ? v1 : v0;
  u16* aggb = r ? o1 : o0;

  int dst = order[i >> 2], h = i & 3;
  float qv[HD];
  {
    const uint4* qp = (const uint4*)(qT + (size_t)dst * HID + h * HD);
#pragma unroll
    for (int j = 0; j < 4; ++j) up8(qp[j], qv + j * 8);
  }
  float acc[HD];
#pragma unroll
  for (int j = 0; j < HD; ++j) acc[j] = 0.f;
  float z = 0.f;
  int b = rowptr[dst], e2 = rowptr[dst + 1];
  int idx = b;
  for (; idx + 2 <= e2; idx += 2) {
    int s0 = srcs[idx], s1 = srcs[idx + 1];
    const uint4* kp0 = (const uint4*)(kT + (size_t)s0 * HID + h * HD);
    const uint4* vp0 = (const uint4*)(vT + (size_t)s0 * HID + h * HD);
    const uint4* kp1 = (const uint4*)(kT + (size_t)s1 * HID + h * HD);
    const uint4* vp1 = (const uint4*)(vT + (size_t)s1 * HID + h * HD);
    uint4 kA = kp0[0], kB = kp0[1];
    uint4 kC = kp1[0], kD = kp1[1];
    uint4 vA = vp0[0], vB = vp0[1];
    uint4 vC = vp1[0], vD = vp1[1];
    float d0 = dot32(kA, kB, qv);
    float d1 = dot32(kC, kD, qv);
    float ev0 = __expf(fminf(d0, 60.f));
    float ev1 = __expf(fminf(d1, 60.f));
    z += ev0 + ev1;
    acc32(vA, vB, ev0, acc);
    acc32(vC, vD, ev1, acc);
  }
  if (idx < e2) {
    int s0 = srcs[idx];
    const uint4* kp0 = (const uint4*)(kT + (size_t)s0 * HID + h * HD);
    const uint4* vp0 = (const uint4*)(vT + (size_t)s0 * HID + h * HD);
    uint4 kA = kp0[0], kB = kp0[1];
    uint4 vA = vp0[0], vB = vp0[1];
    float d0 = dot32(kA, kB, qv);
    float ev0 = __expf(fminf(d0, 60.f));
    z += ev0;
    acc32(vA, vB, ev0, acc);
  }
  float inv = 1.f / (z + 1e-16f);
  u16* ap = aggb + (size_t)dst * HID + h * HD;
  u32 w[16];
#pragma unroll
  for (int j = 0; j < 16; ++j) {
    float a0 = geluf(acc[2 * j] * inv);
    float a1 = geluf(acc[2 * j + 1] * inv);
    w[j] = (u32)f2b(a0) | ((u32)f2b(a1) << 16);
  }
#pragma unroll
  for (int j = 0; j < 4; ++j)
    *(uint4*)(ap + j * 8) = make_uint4(w[4 * j], w[4 * j + 1], w[4 * j + 2], w[4 * j + 3]);
}

extern "C" void kernel_launch(void* const* d_in, const int* in_sizes, int n_in,
                              void* d_out, int out_size, void* d_ws, size_t ws_size,
                              hipStream_t stream) {
  const float* x_user = (const float*)d_in[0];
  const float* x_item = (const float*)d_in[1];
  const float* W_in = (const float*)d_in[2];
  const float* b_in = (const float*)d_in[3];
  const float* Wk = (const float*)d_in[4];
  const float* bk = (const float*)d_in[5];
  const float* Wq = (const float*)d_in[6];
  const float* bq = (const float*)d_in[7];
  const float* Wv = (const float*)d_in[8];
  const float* bv = (const float*)d_in[9];
  const float* a_rel = (const float*)d_in[10];
  const float* m_rel = (const float*)d_in[11];
  const float* p_rel = (const float*)d_in[12];
  const float* Wo = (const float*)d_in[13];
  const float* bo = (const float*)d_in[14];
  const float* skipP = (const float*)d_in[15];
  const int* edge_ui = (const int*)d_in[16];
  const int* edge_iu = (const int*)d_in[17];
  float* out = (float*)d_out;

  char* p = (char*)d_ws;
  auto take = [&](size_t bytes) {
    void* r = (void*)p;
    p += (bytes + 255) & ~(size_t)255;
    return r;
  };
  size_t nodeB = (size_t)NN * HID * sizeof(u16);
  size_t node8 = (size_t)NN * HID;
  u16* hb[2] = {(u16*)take(nodeB), (u16*)take(nodeB)};         // bf16 h (in-place updated)
  u16* qb[2] = {(u16*)take(nodeB), (u16*)take(nodeB)};         // bf16 q
  u8* kb[2] = {(u8*)take(node8), (u8*)take(node8)};            // fp8 k
  u8* vb[2] = {(u8*)take(node8), (u8*)take(node8)};            // fp8 v
  u16* aggb[2] = {(u16*)take(nodeB), (u16*)take(nodeB)};       // gelu'd agg bf16
  int* deg2   = (int*)take((size_t)2 * NN * 4);
  int* cur2   = (int*)take((size_t)2 * NN * 4);
  int* bsum2  = (int*)take((size_t)2 * NB * 4);
  int* boff2  = (int*)take((size_t)2 * NB * 4);
  int* hist2  = (int*)take((size_t)2 * 64 * 4);
  int* hcur2  = (int*)take((size_t)2 * 64 * 4);
  int* rp2    = (int*)take((size_t)2 * (NN + 1) * 4);
  int* srcs[2]  = {(int*)take((size_t)NE * 4), (int*)take((size_t)NE * 4)};
  int* order[2] = {(int*)take((size_t)NN * 4), (int*)take((size_t)NN * 4)};
  u16* winT  = (u16*)take((size_t)2 * HID * HID * 2);
  u16* woT   = (u16*)take((size_t)4 * HID * HID * 2);
  u16* wqkvT = (u16*)take((size_t)2 * 2 * 3 * HID * HID * 2);  // [l][t][q,k,v]
  float* bqkv = (float*)take((size_t)2 * 2 * 3 * HID * 4);
  size_t used = (size_t)(p - (char*)d_ws);
  if (used > ws_size) {
    fprintf(stderr, "HGT kernel: workspace too small: need %zu, have %zu\n", used, ws_size);
    return;
  }

  const int GB = (NN + 127) / 128;
  const int EB = (NE + 255) / 256;
  dim3 blk(256);

  // ---- prologue: 7 dispatches ----
  hipMemsetAsync(deg2, 0, (size_t)2 * NN * 4, stream);
  prep_all<<<dim3(64, 18), blk, 0, stream>>>(W_in, Wo, Wq, bq, Wk, bk, Wv, bv,
                                             a_rel, m_rel, p_rel,
                                             winT, woT, wqkvT, bqkv);
  csr_count<<<dim3(EB, 2), blk, 0, stream>>>(edge_ui, edge_iu, deg2, hist2);
  scan1<<<dim3(NB, 2), SCANB, 0, stream>>>(deg2, rp2, bsum2, hist2);
  scan2<<<dim3(1, 2), 128, 0, stream>>>(bsum2, boff2, hist2, hcur2);
  scan3<<<dim3(NB, 2), SCANB, 0, stream>>>(rp2, cur2, boff2, deg2, hcur2,
                                           order[0], order[1]);
  csr_fill<<<dim3(EB, 2), blk, 0, stream>>>(edge_ui, edge_iu, cur2, srcs[0], srcs[1]);
  int* rowptr[2] = {rp2, rp2 + (NN + 1)};

  // ---- input linear + relu (x fp32 read; h bf16 via transpose stores) ----
  mfgemm<1, true, false, false, true><<<2 * GB, blk, 0, stream>>>(
      x_user, x_item, NN, GB, winT, HID * HID, b_in, HID,
      hb[0], nullptr, nullptr, hb[1], nullptr, nullptr,
      nullptr, nullptr, nullptr, nullptr, nullptr, 0);

  const int AGB = (NN * NH + 255) / 256;
  for (int l = 0; l < LL; ++l) {
    qkv_gemm<<<2 * GB, blk, 0, stream>>>(
        hb[0], hb[1],
        wqkvT + (size_t)l * 2 * 3 * HID * HID,
        bqkv + (size_t)l * 2 * 3 * HID,
        qb[0], qb[1], kb[0], kb[1], vb[0], vb[1], GB);
    agg_csr<<<2 * AGB, blk, 0, stream>>>(
        rowptr[0], srcs[0], order[0], qb[1], kb[0], vb[0], aggb[1],
        rowptr[1], srcs[1], order[1], qb[0], kb[1], vb[1], aggb[0], AGB);
    if (l == 0) {
      mfgemm<1, false, true, false, false><<<2 * GB, blk, 0, stream>>>(
          aggb[0], aggb[1], NN, GB,
          woT, HID * HID, bo, HID,
          hb[0], nullptr, nullptr, hb[1], nullptr, nullptr,
          nullptr, nullptr, hb[0], hb[1], skipP, 0);
    } else {
      mfgemm<1, false, true, false, false><<<2 * GB, blk, 0, stream>>>(
          aggb[0], aggb[1], NN, GB,
          woT + (size_t)2 * HID * HID, HID * HID, bo + 2 * HID, HID,
          nullptr, nullptr, nullptr, nullptr, nullptr, nullptr,
          out, out + (size_t)NN * HID, hb[0], hb[1], skipP + 2, 1);
    }
  }
}